// Round 1
// baseline (5584.348 us; speedup 1.0000x reference)
//
#include <hip/hip_runtime.h>

#define EPS 1e-5f
constexpr int BN = 131072;

// ---- workspace layout (float offsets) ----
constexpr size_t OFF_H   = 0;                         // (B,10) attn1 out
constexpr size_t OFF_HH  = OFF_H  + (size_t)BN*10;    // (B,10) attn2 out
constexpr size_t OFF_M1  = OFF_HH + (size_t)BN*10;    // 65 moments
constexpr size_t OFF_S2  = OFF_M1 + 65;               // 512 sum/sumsq
constexpr size_t OFF_M3  = OFF_S2 + 512;              // 65
constexpr size_t OFF_S4  = OFF_M3 + 65;               // 512
constexpr size_t OFF_WA1 = OFF_S4 + 512;              // 128x10 folded BN1 (transposed)
constexpr size_t OFF_BA1 = OFF_WA1 + 1280;            // 128
constexpr size_t OFF_WB1 = OFF_BA1 + 128;             // 128x256 folded BN2
constexpr size_t OFF_BB1 = OFF_WB1 + 32768;           // 256
constexpr size_t OFF_WA2 = OFF_BB1 + 256;             // 128x10 folded BN3 (transposed)
constexpr size_t OFF_BA2 = OFF_WA2 + 1280;            // 128
constexpr size_t OFF_WB2 = OFF_BA2 + 128;             // 128x256 folded BN4
constexpr size_t OFF_BB2 = OFF_WB2 + 32768;           // 256

__device__ __forceinline__ float wsum(float v){
  v += __shfl_down(v, 32);
  v += __shfl_down(v, 16);
  v += __shfl_down(v, 8);
  v += __shfl_down(v, 4);
  v += __shfl_down(v, 2);
  v += __shfl_down(v, 1);
  return v;
}

// attention on a 10-vector: softmax over q (axis=1!) per column k
__device__ __forceinline__ void attn10(const float* xr, float cqk, float cvo, float* y){
  #pragma unroll
  for (int q=0;q<10;q++) y[q] = 0.f;
  #pragma unroll
  for (int k=0;k<10;k++){
    float t = cqk * xr[k];
    float m = t*xr[0];
    #pragma unroll
    for (int q=1;q<10;q++) m = fmaxf(m, t*xr[q]);
    float ex[10]; float s = 0.f;
    #pragma unroll
    for (int q=0;q<10;q++){ ex[q] = __expf(t*xr[q]-m); s += ex[q]; }
    float f = xr[k]/s;
    #pragma unroll
    for (int q=0;q<10;q++) y[q] += ex[q]*f;
  }
  #pragma unroll
  for (int q=0;q<10;q++) y[q] *= cvo;
}

// reduce 10 sums + 55 upper-tri products of y into M[65]
__device__ __forceinline__ void moments10(const float* y, float* M, int lane){
  #pragma unroll
  for (int i=0;i<10;i++){
    float s = wsum(y[i]);
    if (lane==0) atomicAdd(&M[i], s);
  }
  #pragma unroll
  for (int i=0;i<10;i++){
    #pragma unroll
    for (int j=i;j<10;j++){
      int id = 10*i - i*(i-1)/2 + (j-i);
      float s = wsum(y[i]*y[j]);
      if (lane==0) atomicAdd(&M[10+id], s);
    }
  }
}

// K1: x -> attn1 -> h  (+ 65 moments for BN1)
__global__ __launch_bounds__(256) void k_attn_in(
    const float* __restrict__ x,
    const float* __restrict__ Wq, const float* __restrict__ Wk,
    const float* __restrict__ Wv, const float* __restrict__ Wo,
    float* __restrict__ h, float* __restrict__ M){
  int b = blockIdx.x*256 + threadIdx.x;
  if (b >= BN) return;
  float cqk=0.f, cvo=0.f;
  #pragma unroll
  for (int d=0;d<16;d++){ cqk += Wq[d]*Wk[d]; cvo += Wv[d]*Wo[d]; }
  cqk *= 0.25f;
  float xr[10];
  #pragma unroll
  for (int q=0;q<10;q++) xr[q] = x[(size_t)b*10+q];
  float y[10];
  attn10(xr, cqk, cvo, y);
  #pragma unroll
  for (int q=0;q<10;q++) h[(size_t)b*10+q] = y[q];
  moments10(y, M, threadIdx.x & 63);
}

// fold BN over a (10,128) layer using 10-dim moments -> WT (128,10), bo (128)
__global__ void k_fold10(const float* __restrict__ M,
                         const float* __restrict__ W,
                         const float* __restrict__ bv, const float* __restrict__ g,
                         const float* __restrict__ be,
                         float* __restrict__ WT, float* __restrict__ bo){
  int j = threadIdx.x;
  if (j >= 128) return;
  const float invB = 1.f/(float)BN;
  float Eh[10];
  #pragma unroll
  for (int i=0;i<10;i++) Eh[i] = M[i]*invB;
  float wj[10];
  #pragma unroll
  for (int i=0;i<10;i++) wj[i] = W[i*128+j];
  float mu = bv[j];
  #pragma unroll
  for (int i=0;i<10;i++) mu += Eh[i]*wj[i];
  float var = 0.f;
  #pragma unroll
  for (int i=0;i<10;i++){
    #pragma unroll
    for (int l=0;l<10;l++){
      int a = i<l ? i : l, c = i<l ? l : i;
      int id = 10*a - a*(a-1)/2 + (c-a);
      float cov = M[10+id]*invB - Eh[i]*Eh[l];
      var += wj[i]*wj[l]*cov;
    }
  }
  float s = g[j]*rsqrtf(var + EPS);
  #pragma unroll
  for (int i=0;i<10;i++) WT[j*10+i] = wj[i]*s;
  bo[j] = (bv[j]-mu)*s + be[j];
}

// fold BN over a (128,256) layer using direct sum/sumsq stats
__global__ void k_fold_big(const float* __restrict__ stats,
                           const float* __restrict__ W,
                           const float* __restrict__ bv, const float* __restrict__ g,
                           const float* __restrict__ be,
                           float* __restrict__ Wf, float* __restrict__ bf){
  int j = blockIdx.x*256 + threadIdx.x;
  if (j >= 256) return;
  const float invB = 1.f/(float)BN;
  float mu  = stats[j]*invB;
  float var = stats[256+j]*invB - mu*mu;
  float s = g[j]*rsqrtf(var + EPS);
  bf[j] = (bv[j]-mu)*s + be[j];
  for (int i=0;i<128;i++) Wf[i*256+j] = W[i*256+j]*s;
}

// K2/K4: h(B,10) -> h1=relu(folded) -> z=h1@Wb+bb ; accumulate sum/sumsq of z (not stored)
__global__ __launch_bounds__(256) void k_mid(
    const float* __restrict__ h,
    const float* __restrict__ WaT, const float* __restrict__ ba,
    const float* __restrict__ Wb,  const float* __restrict__ bb,
    float* __restrict__ stats){
  int b = blockIdx.x*256 + threadIdx.x;
  if (b >= BN) return;
  float hr[10];
  #pragma unroll
  for (int l=0;l<10;l++) hr[l] = h[(size_t)b*10+l];
  int lane = threadIdx.x & 63;
  for (int jc=0;jc<4;jc++){
    float acc[64];
    #pragma unroll
    for (int j=0;j<64;j++) acc[j] = bb[jc*64+j];
    for (int i=0;i<128;i++){
      float h1 = ba[i];
      #pragma unroll
      for (int l=0;l<10;l++) h1 += hr[l]*WaT[i*10+l];
      h1 = fmaxf(h1, 0.f);
      const float* __restrict__ w = &Wb[i*256 + jc*64];
      #pragma unroll
      for (int j=0;j<64;j++) acc[j] += h1*w[j];
    }
    #pragma unroll
    for (int j=0;j<64;j++){
      float s1 = wsum(acc[j]);
      float s2 = wsum(acc[j]*acc[j]);
      if (lane==0){
        atomicAdd(&stats[jc*64+j], s1);
        atomicAdd(&stats[256+jc*64+j], s2);
      }
    }
  }
}

// K3: h -> h1 -> h2=relu(folded BN2) -> z3=h2@W1c+b1c -> attn2 -> hh (+ moments)
__global__ __launch_bounds__(256) void k_mid2(
    const float* __restrict__ h,
    const float* __restrict__ WaT, const float* __restrict__ ba,
    const float* __restrict__ Wbf, const float* __restrict__ bbf,
    const float* __restrict__ Wc,  const float* __restrict__ bc,
    const float* __restrict__ Wq, const float* __restrict__ Wk,
    const float* __restrict__ Wv, const float* __restrict__ Wo,
    float* __restrict__ hh, float* __restrict__ M){
  int b = blockIdx.x*256 + threadIdx.x;
  if (b >= BN) return;
  float hr[10];
  #pragma unroll
  for (int l=0;l<10;l++) hr[l] = h[(size_t)b*10+l];
  float z3[10];
  #pragma unroll
  for (int l=0;l<10;l++) z3[l] = bc[l];
  for (int jc=0;jc<4;jc++){
    float acc[64];
    #pragma unroll
    for (int j=0;j<64;j++) acc[j] = bbf[jc*64+j];
    for (int i=0;i<128;i++){
      float h1 = ba[i];
      #pragma unroll
      for (int l=0;l<10;l++) h1 += hr[l]*WaT[i*10+l];
      h1 = fmaxf(h1, 0.f);
      const float* __restrict__ w = &Wbf[i*256 + jc*64];
      #pragma unroll
      for (int j=0;j<64;j++) acc[j] += h1*w[j];
    }
    #pragma unroll
    for (int j=0;j<64;j++){
      float h2 = fmaxf(acc[j], 0.f);
      const float* __restrict__ wc = &Wc[(jc*64+j)*10];
      #pragma unroll
      for (int l=0;l<10;l++) z3[l] += h2*wc[l];
    }
  }
  float cqk=0.f, cvo=0.f;
  #pragma unroll
  for (int d=0;d<16;d++){ cqk += Wq[d]*Wk[d]; cvo += Wv[d]*Wo[d]; }
  cqk *= 0.25f;
  float y[10];
  attn10(z3, cqk, cvo, y);
  #pragma unroll
  for (int q=0;q<10;q++) hh[(size_t)b*10+q] = y[q];
  moments10(y, M, threadIdx.x & 63);
}

// K5: hh -> h4 -> h5=relu(folded BN4) -> out = h5@W2c + b2c
__global__ __launch_bounds__(256) void k_out(
    const float* __restrict__ h,
    const float* __restrict__ WaT, const float* __restrict__ ba,
    const float* __restrict__ Wbf, const float* __restrict__ bbf,
    const float* __restrict__ Wc,  const float* __restrict__ bc,
    float* __restrict__ out){
  int b = blockIdx.x*256 + threadIdx.x;
  if (b >= BN) return;
  float hr[10];
  #pragma unroll
  for (int l=0;l<10;l++) hr[l] = h[(size_t)b*10+l];
  float o0 = bc[0], o1 = bc[1];
  for (int jc=0;jc<4;jc++){
    float acc[64];
    #pragma unroll
    for (int j=0;j<64;j++) acc[j] = bbf[jc*64+j];
    for (int i=0;i<128;i++){
      float h4 = ba[i];
      #pragma unroll
      for (int l=0;l<10;l++) h4 += hr[l]*WaT[i*10+l];
      h4 = fmaxf(h4, 0.f);
      const float* __restrict__ w = &Wbf[i*256 + jc*64];
      #pragma unroll
      for (int j=0;j<64;j++) acc[j] += h4*w[j];
    }
    #pragma unroll
    for (int j=0;j<64;j++){
      float h5 = fmaxf(acc[j], 0.f);
      o0 += h5*Wc[(jc*64+j)*2];
      o1 += h5*Wc[(jc*64+j)*2+1];
    }
  }
  out[(size_t)b*2]   = o0;
  out[(size_t)b*2+1] = o1;
}

extern "C" void kernel_launch(void* const* d_in, const int* in_sizes, int n_in,
                              void* d_out, int out_size, void* d_ws, size_t ws_size,
                              hipStream_t stream){
  const float* x   = (const float*)d_in[0];
  const float* Wq1 = (const float*)d_in[1];
  const float* Wk1 = (const float*)d_in[2];
  const float* Wv1 = (const float*)d_in[3];
  const float* Wo1 = (const float*)d_in[4];
  const float* Wq2 = (const float*)d_in[5];
  const float* Wk2 = (const float*)d_in[6];
  const float* Wv2 = (const float*)d_in[7];
  const float* Wo2 = (const float*)d_in[8];
  const float* W1a = (const float*)d_in[9];  const float* b1a = (const float*)d_in[10];
  const float* g1a = (const float*)d_in[11]; const float* be1a= (const float*)d_in[12];
  const float* W1b = (const float*)d_in[13]; const float* b1b = (const float*)d_in[14];
  const float* g1b = (const float*)d_in[15]; const float* be1b= (const float*)d_in[16];
  const float* W1c = (const float*)d_in[17]; const float* b1c = (const float*)d_in[18];
  const float* W2a = (const float*)d_in[19]; const float* b2a = (const float*)d_in[20];
  const float* g2a = (const float*)d_in[21]; const float* be2a= (const float*)d_in[22];
  const float* W2b = (const float*)d_in[23]; const float* b2b = (const float*)d_in[24];
  const float* g2b = (const float*)d_in[25]; const float* be2b= (const float*)d_in[26];
  const float* W2c = (const float*)d_in[27]; const float* b2c = (const float*)d_in[28];

  float* f   = (float*)d_ws;
  float* h   = f + OFF_H;
  float* hh  = f + OFF_HH;
  float* M1  = f + OFF_M1;
  float* S2  = f + OFF_S2;
  float* M3  = f + OFF_M3;
  float* S4  = f + OFF_S4;
  float* WA1 = f + OFF_WA1; float* BA1 = f + OFF_BA1;
  float* WB1 = f + OFF_WB1; float* BB1 = f + OFF_BB1;
  float* WA2 = f + OFF_WA2; float* BA2 = f + OFF_BA2;
  float* WB2 = f + OFF_WB2; float* BB2 = f + OFF_BB2;

  hipMemsetAsync(M1, 0, (65+512+65+512)*sizeof(float), stream);

  dim3 grid(BN/256), blk(256);
  k_attn_in<<<grid,blk,0,stream>>>(x, Wq1,Wk1,Wv1,Wo1, h, M1);
  k_fold10<<<1,128,0,stream>>>(M1, W1a,b1a,g1a,be1a, WA1,BA1);
  k_mid<<<grid,blk,0,stream>>>(h, WA1,BA1, W1b,b1b, S2);
  k_fold_big<<<1,256,0,stream>>>(S2, W1b,b1b,g1b,be1b, WB1,BB1);
  k_mid2<<<grid,blk,0,stream>>>(h, WA1,BA1, WB1,BB1, W1c,b1c, Wq2,Wk2,Wv2,Wo2, hh, M3);
  k_fold10<<<1,128,0,stream>>>(M3, W2a,b2a,g2a,be2a, WA2,BA2);
  k_mid<<<grid,blk,0,stream>>>(hh, WA2,BA2, W2b,b2b, S4);
  k_fold_big<<<1,256,0,stream>>>(S4, W2b,b2b,g2b,be2b, WB2,BB2);
  k_out<<<grid,blk,0,stream>>>(hh, WA2,BA2, WB2,BB2, W2c,b2c, (float*)d_out);
}

// Round 2
// 2676.437 us; speedup vs baseline: 2.0865x; 2.0865x over previous
//
#include <hip/hip_runtime.h>
#include <hip/hip_bf16.h>

#define EPS 1e-5f
constexpr int BN = 131072;

// ---- workspace layout (float offsets) ----
constexpr size_t OFF_H   = 0;                         // (B,10) attn1 out
constexpr size_t OFF_HH  = OFF_H  + (size_t)BN*10;    // (B,10) attn2 out
constexpr size_t OFF_M1  = OFF_HH + (size_t)BN*10;    // 65 moments
constexpr size_t OFF_S2  = OFF_M1 + 65;               // 512 sum/sumsq
constexpr size_t OFF_M3  = OFF_S2 + 512;              // 65
constexpr size_t OFF_S4  = OFF_M3 + 65;               // 512
constexpr size_t OFF_WA1 = OFF_S4 + 512;              // 128x10 folded BN1 (transposed)
constexpr size_t OFF_BA1 = OFF_WA1 + 1280;            // 128
constexpr size_t OFF_WA2 = OFF_BA1 + 128;             // 128x10 folded BN3 (transposed)
constexpr size_t OFF_BA2 = OFF_WA2 + 1280;            // 128
constexpr size_t OFF_SC2 = OFF_BA2 + 128;             // 256 BN2 scale
constexpr size_t OFF_TC2 = OFF_SC2 + 256;             // 256 BN2 shift
constexpr size_t OFF_SC4 = OFF_TC2 + 256;             // 256 BN4 scale
constexpr size_t OFF_TC4 = OFF_SC4 + 256;             // 256 BN4 shift
constexpr size_t OFF_WB1 = OFF_TC4 + 256;             // 128x256 folded (fallback path)
constexpr size_t OFF_BB1 = OFF_WB1 + 32768;           // 256
constexpr size_t OFF_WB2 = OFF_BB1 + 256;             // 128x256 folded (fallback path)
constexpr size_t OFF_BB2 = OFF_WB2 + 32768;           // 256
constexpr size_t OFF_END = OFF_BB2 + 256;             // floats
constexpr size_t OFF_Z_BYTES = ((OFF_END*4 + 255) & ~(size_t)255); // bf16 z buffer
constexpr size_t WS_NEED = OFF_Z_BYTES + (size_t)BN*256*2;

__device__ __forceinline__ float wsum(float v){
  v += __shfl_down(v, 32);
  v += __shfl_down(v, 16);
  v += __shfl_down(v, 8);
  v += __shfl_down(v, 4);
  v += __shfl_down(v, 2);
  v += __shfl_down(v, 1);
  return v;
}

__device__ __forceinline__ unsigned pk_bf16(float a, float b){
  union { __hip_bfloat16 h[2]; unsigned u; } cv;
  cv.h[0] = __float2bfloat16(a);
  cv.h[1] = __float2bfloat16(b);
  return cv.u;
}

// attention on a 10-vector: softmax over q (axis=1!) per column k
__device__ __forceinline__ void attn10(const float* xr, float cqk, float cvo, float* y){
  #pragma unroll
  for (int q=0;q<10;q++) y[q] = 0.f;
  #pragma unroll
  for (int k=0;k<10;k++){
    float t = cqk * xr[k];
    float m = t*xr[0];
    #pragma unroll
    for (int q=1;q<10;q++) m = fmaxf(m, t*xr[q]);
    float ex[10]; float s = 0.f;
    #pragma unroll
    for (int q=0;q<10;q++){ ex[q] = __expf(t*xr[q]-m); s += ex[q]; }
    float f = xr[k]/s;
    #pragma unroll
    for (int q=0;q<10;q++) y[q] += ex[q]*f;
  }
  #pragma unroll
  for (int q=0;q<10;q++) y[q] *= cvo;
}

// reduce 10 sums + 55 upper-tri products of y into M[65]
__device__ __forceinline__ void moments10(const float* y, float* M, int lane){
  #pragma unroll
  for (int i=0;i<10;i++){
    float s = wsum(y[i]);
    if (lane==0) atomicAdd(&M[i], s);
  }
  #pragma unroll
  for (int i=0;i<10;i++){
    #pragma unroll
    for (int j=i;j<10;j++){
      int id = 10*i - i*(i-1)/2 + (j-i);
      float s = wsum(y[i]*y[j]);
      if (lane==0) atomicAdd(&M[10+id], s);
    }
  }
}

// K1: x -> attn1 -> h  (+ 65 moments for BN1)
__global__ __launch_bounds__(256) void k_attn_in(
    const float* __restrict__ x,
    const float* __restrict__ Wq, const float* __restrict__ Wk,
    const float* __restrict__ Wv, const float* __restrict__ Wo,
    float* __restrict__ h, float* __restrict__ M){
  int b = blockIdx.x*256 + threadIdx.x;
  if (b >= BN) return;
  float cqk=0.f, cvo=0.f;
  #pragma unroll
  for (int d=0;d<16;d++){ cqk += Wq[d]*Wk[d]; cvo += Wv[d]*Wo[d]; }
  cqk *= 0.25f;
  float xr[10];
  #pragma unroll
  for (int q=0;q<10;q++) xr[q] = x[(size_t)b*10+q];
  float y[10];
  attn10(xr, cqk, cvo, y);
  #pragma unroll
  for (int q=0;q<10;q++) h[(size_t)b*10+q] = y[q];
  moments10(y, M, threadIdx.x & 63);
}

// fold BN over a (10,128) layer using 10-dim moments -> WT (128,10), bo (128)
__global__ void k_fold10(const float* __restrict__ M,
                         const float* __restrict__ W,
                         const float* __restrict__ bv, const float* __restrict__ g,
                         const float* __restrict__ be,
                         float* __restrict__ WT, float* __restrict__ bo){
  int j = threadIdx.x;
  if (j >= 128) return;
  const float invB = 1.f/(float)BN;
  float Eh[10];
  #pragma unroll
  for (int i=0;i<10;i++) Eh[i] = M[i]*invB;
  float wj[10];
  #pragma unroll
  for (int i=0;i<10;i++) wj[i] = W[i*128+j];
  float mu = bv[j];
  #pragma unroll
  for (int i=0;i<10;i++) mu += Eh[i]*wj[i];
  float var = 0.f;
  #pragma unroll
  for (int i=0;i<10;i++){
    #pragma unroll
    for (int l=0;l<10;l++){
      int a = i<l ? i : l, c = i<l ? l : i;
      int id = 10*a - a*(a-1)/2 + (c-a);
      float cov = M[10+id]*invB - Eh[i]*Eh[l];
      var += wj[i]*wj[l]*cov;
    }
  }
  float s = g[j]*rsqrtf(var + EPS);
  #pragma unroll
  for (int i=0;i<10;i++) WT[j*10+i] = wj[i]*s;
  bo[j] = (bv[j]-mu)*s + be[j];
}

// BN fold as per-column affine: s = g*rsqrt(var+eps), t = be - mu*s
__global__ void k_fold_affine(const float* __restrict__ stats,
                              const float* __restrict__ g,
                              const float* __restrict__ be,
                              float* __restrict__ s, float* __restrict__ tt){
  int j = threadIdx.x;
  if (j >= 256) return;
  const float invB = 1.f/(float)BN;
  float mu  = stats[j]*invB;
  float var = stats[256+j]*invB - mu*mu;
  float sc = g[j]*rsqrtf(var + EPS);
  s[j]  = sc;
  tt[j] = be[j] - mu*sc;
}

// ===================== fast path =====================
// fused 10 -> relu(BN-folded 128) -> 256 GEMM; writes z (bf16) + sum/sumsq stats
// block: 256 threads, 64 rows. LDS: h1 transposed [128][68] (pad -> conflict-free b128)
__global__ __launch_bounds__(256) void k_layer_big(
    const float* __restrict__ h,      // (B,10)
    const float* __restrict__ WaT,    // (128,10) folded
    const float* __restrict__ ba,     // (128)
    const float* __restrict__ Wb,     // (128,256) RAW (z is pre-BN)
    const float* __restrict__ bb,     // (256)
    unsigned short* __restrict__ z,   // (B,256) bf16 out
    float* __restrict__ stats)        // 512: sum | sumsq
{
  __shared__ float h1T[128][68];
  __shared__ float hs[64][10];
  __shared__ float sWaT[1280];
  __shared__ float sstats[512];
  int t = threadIdx.x;
  size_t row0 = (size_t)blockIdx.x * 64;

  for (int idx = t; idx < 640; idx += 256) hs[idx/10][idx%10] = h[row0*10 + idx];
  for (int idx = t; idx < 1280; idx += 256) sWaT[idx] = WaT[idx];
  sstats[t] = 0.f; sstats[256+t] = 0.f;
  __syncthreads();

  // phase 1: h1 = relu(h @ WaT' + ba), 32 values per thread
  {
    int r  = t & 63;
    int i0 = (t >> 6) * 32;
    float hr[10];
    #pragma unroll
    for (int l=0;l<10;l++) hr[l] = hs[r][l];
    for (int k=0;k<32;k++){
      int i = i0 + k;
      float v = ba[i];
      #pragma unroll
      for (int l=0;l<10;l++) v = fmaf(hr[l], sWaT[i*10+l], v);
      h1T[i][r] = fmaxf(v, 0.f);
    }
  }
  __syncthreads();

  // phase 2: z = h1 @ Wb + bb ; 4 rows x 16 cols per thread
  int tx = t & 15;   // col group: cols tx*16..+15
  int ty = t >> 4;   // row group: rows ty*4..+3
  float acc[4][16];
  #pragma unroll
  for (int r=0;r<4;r++)
    #pragma unroll
    for (int c=0;c<16;c++) acc[r][c] = 0.f;

  const float* __restrict__ wrow = Wb + tx*16;
  for (int i=0;i<128;i++){
    const float4* wp = (const float4*)(wrow + (size_t)i*256);
    float wv[16];
    #pragma unroll
    for (int q=0;q<4;q++){
      float4 w = wp[q];
      wv[4*q+0]=w.x; wv[4*q+1]=w.y; wv[4*q+2]=w.z; wv[4*q+3]=w.w;
    }
    float4 av = *(const float4*)&h1T[i][ty*4];
    float a4[4] = {av.x, av.y, av.z, av.w};
    #pragma unroll
    for (int r=0;r<4;r++)
      #pragma unroll
      for (int c=0;c<16;c++)
        acc[r][c] = fmaf(a4[r], wv[c], acc[r][c]);
  }

  // epilogue: +bias, store bf16 z, stats
  #pragma unroll
  for (int r=0;r<4;r++){
    unsigned p[8];
    #pragma unroll
    for (int q=0;q<8;q++){
      float z0 = acc[r][2*q]   + bb[tx*16 + 2*q];
      float z1 = acc[r][2*q+1] + bb[tx*16 + 2*q+1];
      acc[r][2*q]   = z0;
      acc[r][2*q+1] = z1;
      p[q] = pk_bf16(z0, z1);
    }
    uint4* zp = (uint4*)(z + (row0 + ty*4 + r)*256 + tx*16);
    zp[0] = make_uint4(p[0],p[1],p[2],p[3]);
    zp[1] = make_uint4(p[4],p[5],p[6],p[7]);
  }
  int lane = t & 63;
  #pragma unroll
  for (int c=0;c<16;c++){
    float s1 = acc[0][c]+acc[1][c]+acc[2][c]+acc[3][c];
    float q1 = acc[0][c]*acc[0][c]+acc[1][c]*acc[1][c]
             + acc[2][c]*acc[2][c]+acc[3][c]*acc[3][c];
    s1 += __shfl_down(s1, 32); s1 += __shfl_down(s1, 16);
    q1 += __shfl_down(q1, 32); q1 += __shfl_down(q1, 16);
    if (lane < 16){
      atomicAdd(&sstats[tx*16+c], s1);
      atomicAdd(&sstats[256+tx*16+c], q1);
    }
  }
  __syncthreads();
  atomicAdd(&stats[t], sstats[t]);
  atomicAdd(&stats[256+t], sstats[256+t]);
}

// consume z1: h2 = relu(s*z+t) -> z3 = h2 @ Wc(256,10) + bc -> attn2 -> hh, M3
__global__ __launch_bounds__(256) void k_consume_mid(
    const unsigned short* __restrict__ z,
    const float* __restrict__ s_g, const float* __restrict__ t_g,
    const float* __restrict__ Wc,  const float* __restrict__ bc,
    const float* __restrict__ Wq, const float* __restrict__ Wk,
    const float* __restrict__ Wv, const float* __restrict__ Wo,
    float* __restrict__ hh, float* __restrict__ M){
  __shared__ float sW[2560];
  __shared__ float ss[256], st[256];
  int t = threadIdx.x;
  for (int idx=t; idx<2560; idx+=256) sW[idx] = Wc[idx];
  ss[t] = s_g[t]; st[t] = t_g[t];
  __syncthreads();
  size_t b = (size_t)blockIdx.x*256 + t;
  float z3[10];
  #pragma unroll
  for (int l=0;l<10;l++) z3[l] = bc[l];
  const uint4* zr = (const uint4*)(z + b*256);
  for (int v=0; v<32; v++){
    uint4 pkt = zr[v];
    unsigned w4[4] = {pkt.x, pkt.y, pkt.z, pkt.w};
    #pragma unroll
    for (int q=0;q<4;q++){
      int j = v*8 + q*2;
      float f0 = __uint_as_float(w4[q] << 16);
      float f1 = __uint_as_float(w4[q] & 0xffff0000u);
      float h20 = fmaxf(fmaf(ss[j],   f0, st[j]),   0.f);
      float h21 = fmaxf(fmaf(ss[j+1], f1, st[j+1]), 0.f);
      #pragma unroll
      for (int l=0;l<10;l++) z3[l] = fmaf(h20, sW[j*10+l], z3[l]);
      #pragma unroll
      for (int l=0;l<10;l++) z3[l] = fmaf(h21, sW[(j+1)*10+l], z3[l]);
    }
  }
  float cqk=0.f, cvo=0.f;
  #pragma unroll
  for (int d=0;d<16;d++){ cqk += Wq[d]*Wk[d]; cvo += Wv[d]*Wo[d]; }
  cqk *= 0.25f;
  float y[10];
  attn10(z3, cqk, cvo, y);
  #pragma unroll
  for (int q=0;q<10;q++) hh[b*10+q] = y[q];
  moments10(y, M, t & 63);
}

// consume z2: h5 = relu(s*z+t) -> out = h5 @ Wc(256,2) + bc
__global__ __launch_bounds__(256) void k_consume_out(
    const unsigned short* __restrict__ z,
    const float* __restrict__ s_g, const float* __restrict__ t_g,
    const float* __restrict__ Wc,  const float* __restrict__ bc,
    float* __restrict__ out){
  __shared__ float sW0[256], sW1[256], ss[256], st[256];
  int t = threadIdx.x;
  sW0[t] = Wc[t*2]; sW1[t] = Wc[t*2+1];
  ss[t] = s_g[t]; st[t] = t_g[t];
  __syncthreads();
  size_t b = (size_t)blockIdx.x*256 + t;
  float o0 = bc[0], o1 = bc[1];
  const uint4* zr = (const uint4*)(z + b*256);
  for (int v=0; v<32; v++){
    uint4 pkt = zr[v];
    unsigned w4[4] = {pkt.x, pkt.y, pkt.z, pkt.w};
    #pragma unroll
    for (int q=0;q<4;q++){
      int j = v*8 + q*2;
      float f0 = __uint_as_float(w4[q] << 16);
      float f1 = __uint_as_float(w4[q] & 0xffff0000u);
      float h20 = fmaxf(fmaf(ss[j],   f0, st[j]),   0.f);
      float h21 = fmaxf(fmaf(ss[j+1], f1, st[j+1]), 0.f);
      o0 = fmaf(h20, sW0[j],   o0); o1 = fmaf(h20, sW1[j],   o1);
      o0 = fmaf(h21, sW0[j+1], o0); o1 = fmaf(h21, sW1[j+1], o1);
    }
  }
  out[b*2]   = o0;
  out[b*2+1] = o1;
}

// ===================== fallback path (round-0, verified) =====================
__global__ void k_fold_big(const float* __restrict__ stats,
                           const float* __restrict__ W,
                           const float* __restrict__ bv, const float* __restrict__ g,
                           const float* __restrict__ be,
                           float* __restrict__ Wf, float* __restrict__ bf){
  int j = blockIdx.x*256 + threadIdx.x;
  if (j >= 256) return;
  const float invB = 1.f/(float)BN;
  float mu  = stats[j]*invB;
  float var = stats[256+j]*invB - mu*mu;
  float s = g[j]*rsqrtf(var + EPS);
  bf[j] = (bv[j]-mu)*s + be[j];
  for (int i=0;i<128;i++) Wf[i*256+j] = W[i*256+j]*s;
}

__global__ __launch_bounds__(256) void k_mid(
    const float* __restrict__ h,
    const float* __restrict__ WaT, const float* __restrict__ ba,
    const float* __restrict__ Wb,  const float* __restrict__ bb,
    float* __restrict__ stats){
  int b = blockIdx.x*256 + threadIdx.x;
  if (b >= BN) return;
  float hr[10];
  #pragma unroll
  for (int l=0;l<10;l++) hr[l] = h[(size_t)b*10+l];
  int lane = threadIdx.x & 63;
  for (int jc=0;jc<4;jc++){
    float acc[64];
    #pragma unroll
    for (int j=0;j<64;j++) acc[j] = bb[jc*64+j];
    for (int i=0;i<128;i++){
      float h1 = ba[i];
      #pragma unroll
      for (int l=0;l<10;l++) h1 += hr[l]*WaT[i*10+l];
      h1 = fmaxf(h1, 0.f);
      const float* __restrict__ w = &Wb[i*256 + jc*64];
      #pragma unroll
      for (int j=0;j<64;j++) acc[j] += h1*w[j];
    }
    #pragma unroll
    for (int j=0;j<64;j++){
      float s1 = wsum(acc[j]);
      float s2 = wsum(acc[j]*acc[j]);
      if (lane==0){
        atomicAdd(&stats[jc*64+j], s1);
        atomicAdd(&stats[256+jc*64+j], s2);
      }
    }
  }
}

__global__ __launch_bounds__(256) void k_mid2(
    const float* __restrict__ h,
    const float* __restrict__ WaT, const float* __restrict__ ba,
    const float* __restrict__ Wbf, const float* __restrict__ bbf,
    const float* __restrict__ Wc,  const float* __restrict__ bc,
    const float* __restrict__ Wq, const float* __restrict__ Wk,
    const float* __restrict__ Wv, const float* __restrict__ Wo,
    float* __restrict__ hh, float* __restrict__ M){
  int b = blockIdx.x*256 + threadIdx.x;
  if (b >= BN) return;
  float hr[10];
  #pragma unroll
  for (int l=0;l<10;l++) hr[l] = h[(size_t)b*10+l];
  float z3[10];
  #pragma unroll
  for (int l=0;l<10;l++) z3[l] = bc[l];
  for (int jc=0;jc<4;jc++){
    float acc[64];
    #pragma unroll
    for (int j=0;j<64;j++) acc[j] = bbf[jc*64+j];
    for (int i=0;i<128;i++){
      float h1 = ba[i];
      #pragma unroll
      for (int l=0;l<10;l++) h1 += hr[l]*WaT[i*10+l];
      h1 = fmaxf(h1, 0.f);
      const float* __restrict__ w = &Wbf[i*256 + jc*64];
      #pragma unroll
      for (int j=0;j<64;j++) acc[j] += h1*w[j];
    }
    #pragma unroll
    for (int j=0;j<64;j++){
      float h2 = fmaxf(acc[j], 0.f);
      const float* __restrict__ wc = &Wc[(jc*64+j)*10];
      #pragma unroll
      for (int l=0;l<10;l++) z3[l] += h2*wc[l];
    }
  }
  float cqk=0.f, cvo=0.f;
  #pragma unroll
  for (int d=0;d<16;d++){ cqk += Wq[d]*Wk[d]; cvo += Wv[d]*Wo[d]; }
  cqk *= 0.25f;
  float y[10];
  attn10(z3, cqk, cvo, y);
  #pragma unroll
  for (int q=0;q<10;q++) hh[(size_t)b*10+q] = y[q];
  moments10(y, M, threadIdx.x & 63);
}

__global__ __launch_bounds__(256) void k_out(
    const float* __restrict__ h,
    const float* __restrict__ WaT, const float* __restrict__ ba,
    const float* __restrict__ Wbf, const float* __restrict__ bbf,
    const float* __restrict__ Wc,  const float* __restrict__ bc,
    float* __restrict__ out){
  int b = blockIdx.x*256 + threadIdx.x;
  if (b >= BN) return;
  float hr[10];
  #pragma unroll
  for (int l=0;l<10;l++) hr[l] = h[(size_t)b*10+l];
  float o0 = bc[0], o1 = bc[1];
  for (int jc=0;jc<4;jc++){
    float acc[64];
    #pragma unroll
    for (int j=0;j<64;j++) acc[j] = bbf[jc*64+j];
    for (int i=0;i<128;i++){
      float h4 = ba[i];
      #pragma unroll
      for (int l=0;l<10;l++) h4 += hr[l]*WaT[i*10+l];
      h4 = fmaxf(h4, 0.f);
      const float* __restrict__ w = &Wbf[i*256 + jc*64];
      #pragma unroll
      for (int j=0;j<64;j++) acc[j] += h4*w[j];
    }
    #pragma unroll
    for (int j=0;j<64;j++){
      float h5 = fmaxf(acc[j], 0.f);
      o0 += h5*Wc[(jc*64+j)*2];
      o1 += h5*Wc[(jc*64+j)*2+1];
    }
  }
  out[(size_t)b*2]   = o0;
  out[(size_t)b*2+1] = o1;
}

extern "C" void kernel_launch(void* const* d_in, const int* in_sizes, int n_in,
                              void* d_out, int out_size, void* d_ws, size_t ws_size,
                              hipStream_t stream){
  const float* x   = (const float*)d_in[0];
  const float* Wq1 = (const float*)d_in[1];
  const float* Wk1 = (const float*)d_in[2];
  const float* Wv1 = (const float*)d_in[3];
  const float* Wo1 = (const float*)d_in[4];
  const float* Wq2 = (const float*)d_in[5];
  const float* Wk2 = (const float*)d_in[6];
  const float* Wv2 = (const float*)d_in[7];
  const float* Wo2 = (const float*)d_in[8];
  const float* W1a = (const float*)d_in[9];  const float* b1a = (const float*)d_in[10];
  const float* g1a = (const float*)d_in[11]; const float* be1a= (const float*)d_in[12];
  const float* W1b = (const float*)d_in[13]; const float* b1b = (const float*)d_in[14];
  const float* g1b = (const float*)d_in[15]; const float* be1b= (const float*)d_in[16];
  const float* W1c = (const float*)d_in[17]; const float* b1c = (const float*)d_in[18];
  const float* W2a = (const float*)d_in[19]; const float* b2a = (const float*)d_in[20];
  const float* g2a = (const float*)d_in[21]; const float* be2a= (const float*)d_in[22];
  const float* W2b = (const float*)d_in[23]; const float* b2b = (const float*)d_in[24];
  const float* g2b = (const float*)d_in[25]; const float* be2b= (const float*)d_in[26];
  const float* W2c = (const float*)d_in[27]; const float* b2c = (const float*)d_in[28];

  float* f   = (float*)d_ws;
  float* h   = f + OFF_H;
  float* hh  = f + OFF_HH;
  float* M1  = f + OFF_M1;
  float* S2  = f + OFF_S2;
  float* M3  = f + OFF_M3;
  float* S4  = f + OFF_S4;
  float* WA1 = f + OFF_WA1; float* BA1 = f + OFF_BA1;
  float* WA2 = f + OFF_WA2; float* BA2 = f + OFF_BA2;
  float* SC2 = f + OFF_SC2; float* TC2 = f + OFF_TC2;
  float* SC4 = f + OFF_SC4; float* TC4 = f + OFF_TC4;
  float* WB1 = f + OFF_WB1; float* BB1 = f + OFF_BB1;
  float* WB2 = f + OFF_WB2; float* BB2 = f + OFF_BB2;
  unsigned short* Z = (unsigned short*)((char*)d_ws + OFF_Z_BYTES);

  hipMemsetAsync(M1, 0, (65+512+65+512)*sizeof(float), stream);

  dim3 grid(BN/256), blk(256);
  k_attn_in<<<grid,blk,0,stream>>>(x, Wq1,Wk1,Wv1,Wo1, h, M1);
  k_fold10<<<1,128,0,stream>>>(M1, W1a,b1a,g1a,be1a, WA1,BA1);

  if (ws_size >= WS_NEED){
    dim3 gbig(BN/64);
    k_layer_big<<<gbig,blk,0,stream>>>(h, WA1,BA1, W1b,b1b, Z, S2);
    k_fold_affine<<<1,256,0,stream>>>(S2, g1b, be1b, SC2, TC2);
    k_consume_mid<<<grid,blk,0,stream>>>(Z, SC2,TC2, W1c,b1c, Wq2,Wk2,Wv2,Wo2, hh, M3);
    k_fold10<<<1,128,0,stream>>>(M3, W2a,b2a,g2a,be2a, WA2,BA2);
    k_layer_big<<<gbig,blk,0,stream>>>(hh, WA2,BA2, W2b,b2b, Z, S4);
    k_fold_affine<<<1,256,0,stream>>>(S4, g2b, be2b, SC4, TC4);
    k_consume_out<<<grid,blk,0,stream>>>(Z, SC4,TC4, W2c,b2c, (float*)d_out);
  } else {
    k_mid<<<grid,blk,0,stream>>>(h, WA1,BA1, W1b,b1b, S2);
    k_fold_big<<<1,256,0,stream>>>(S2, W1b,b1b,g1b,be1b, WB1,BB1);
    k_mid2<<<grid,blk,0,stream>>>(h, WA1,BA1, WB1,BB1, W1c,b1c, Wq2,Wk2,Wv2,Wo2, hh, M3);
    k_fold10<<<1,128,0,stream>>>(M3, W2a,b2a,g2a,be2a, WA2,BA2);
    k_mid<<<grid,blk,0,stream>>>(hh, WA2,BA2, W2b,b2b, S4);
    k_fold_big<<<1,256,0,stream>>>(S4, W2b,b2b,g2b,be2b, WB2,BB2);
    k_out<<<grid,blk,0,stream>>>(hh, WA2,BA2, WB2,BB2, W2c,b2c, (float*)d_out);
  }
}

// Round 3
// 702.175 us; speedup vs baseline: 7.9529x; 3.8116x over previous
//
#include <hip/hip_runtime.h>
#include <hip/hip_bf16.h>

#define EPS 1e-5f
constexpr int BN = 131072;
constexpr int NBKT = 32;

// ---- workspace layout (float offsets) ----
constexpr size_t OFF_H   = 0;                         // (B,10) attn1 out
constexpr size_t OFF_HH  = OFF_H  + (size_t)BN*10;    // (B,10) attn2 out
constexpr size_t OFF_M1  = OFF_HH + (size_t)BN*10;    // 65  (fallback)
constexpr size_t OFF_S2  = OFF_M1 + 65;               // 512 (fallback)
constexpr size_t OFF_M3  = OFF_S2 + 512;              // 65  (fallback)
constexpr size_t OFF_S4  = OFF_M3 + 65;               // 512 (fallback)
constexpr size_t OFF_WA1 = OFF_S4 + 512;              // 128x10 folded BN1 (T)
constexpr size_t OFF_BA1 = OFF_WA1 + 1280;            // 128
constexpr size_t OFF_WA2 = OFF_BA1 + 128;             // 128x10 folded BN3 (T)
constexpr size_t OFF_BA2 = OFF_WA2 + 1280;            // 128
constexpr size_t OFF_SC2 = OFF_BA2 + 128;             // 256
constexpr size_t OFF_TC2 = OFF_SC2 + 256;             // 256
constexpr size_t OFF_SC4 = OFF_TC2 + 256;             // 256
constexpr size_t OFF_TC4 = OFF_SC4 + 256;             // 256
constexpr size_t OFF_WB1 = OFF_TC4 + 256;             // 128x256 (fallback)
constexpr size_t OFF_BB1 = OFF_WB1 + 32768;           // 256
constexpr size_t OFF_WB2 = OFF_BB1 + 256;             // 128x256 (fallback)
constexpr size_t OFF_BB2 = OFF_WB2 + 32768;           // 256
constexpr size_t OFF_P1  = OFF_BB2 + 256;             // 512x65 attn1 moment partials
constexpr size_t OFF_P3  = OFF_P1 + 512*65;           // 512x65 attn2 moment partials
constexpr size_t OFF_S2B = OFF_P3 + 512*65;           // NBKT x 512 bucket stats L1
constexpr size_t OFF_S4B = OFF_S2B + (size_t)NBKT*512;// NBKT x 512 bucket stats L2
constexpr size_t OFF_END = OFF_S4B + (size_t)NBKT*512;
constexpr size_t OFF_Z_BYTES = ((OFF_END*4 + 255) & ~(size_t)255); // bf16 z buffer
constexpr size_t WS_NEED = OFF_Z_BYTES + (size_t)BN*256*2;

__device__ __forceinline__ float wsum(float v){
  v += __shfl_down(v, 32);
  v += __shfl_down(v, 16);
  v += __shfl_down(v, 8);
  v += __shfl_down(v, 4);
  v += __shfl_down(v, 2);
  v += __shfl_down(v, 1);
  return v;
}

__device__ __forceinline__ unsigned pk_bf16(float a, float b){
  union { __hip_bfloat16 h[2]; unsigned u; } cv;
  cv.h[0] = __float2bfloat16(a);
  cv.h[1] = __float2bfloat16(b);
  return cv.u;
}

// attention on a 10-vector: softmax over q (axis=1!) per column k
__device__ __forceinline__ void attn10(const float* xr, float cqk, float cvo, float* y){
  #pragma unroll
  for (int q=0;q<10;q++) y[q] = 0.f;
  #pragma unroll
  for (int k=0;k<10;k++){
    float t = cqk * xr[k];
    float m = t*xr[0];
    #pragma unroll
    for (int q=1;q<10;q++) m = fmaxf(m, t*xr[q]);
    float ex[10]; float s = 0.f;
    #pragma unroll
    for (int q=0;q<10;q++){ ex[q] = __expf(t*xr[q]-m); s += ex[q]; }
    float f = xr[k]/s;
    #pragma unroll
    for (int q=0;q<10;q++) y[q] += ex[q]*f;
  }
  #pragma unroll
  for (int q=0;q<10;q++) y[q] *= cvo;
}

// block-level moment reduction: 65 wave-reduces -> LDS -> one partial row per block
__device__ __forceinline__ void moments_block(const float* y, float (*red)[65],
                                              float* Pb, int t){
  int lane = t & 63, w = t >> 6;
  #pragma unroll
  for (int i=0;i<10;i++){
    float v = wsum(y[i]);
    if (lane==0) red[w][i] = v;
  }
  #pragma unroll
  for (int i=0;i<10;i++){
    #pragma unroll
    for (int j=i;j<10;j++){
      float v = wsum(y[i]*y[j]);
      if (lane==0) red[w][10 + 10*i - i*(i-1)/2 + (j-i)] = v;
    }
  }
  __syncthreads();
  if (t < 65)
    Pb[(size_t)blockIdx.x*65 + t] = red[0][t]+red[1][t]+red[2][t]+red[3][t];
}

// legacy atomic moments (fallback path only)
__device__ __forceinline__ void moments10(const float* y, float* M, int lane){
  #pragma unroll
  for (int i=0;i<10;i++){
    float s = wsum(y[i]);
    if (lane==0) atomicAdd(&M[i], s);
  }
  #pragma unroll
  for (int i=0;i<10;i++){
    #pragma unroll
    for (int j=i;j<10;j++){
      int id = 10*i - i*(i-1)/2 + (j-i);
      float s = wsum(y[i]*y[j]);
      if (lane==0) atomicAdd(&M[10+id], s);
    }
  }
}

// K1: x -> attn1 -> h  (+ per-block moment partials)
__global__ __launch_bounds__(256) void k_attn_in(
    const float* __restrict__ x,
    const float* __restrict__ Wq, const float* __restrict__ Wk,
    const float* __restrict__ Wv, const float* __restrict__ Wo,
    float* __restrict__ h, float* __restrict__ Pb){
  __shared__ float red[4][65];
  int t = threadIdx.x;
  size_t b = (size_t)blockIdx.x*256 + t;
  float cqk=0.f, cvo=0.f;
  #pragma unroll
  for (int d=0;d<16;d++){ cqk += Wq[d]*Wk[d]; cvo += Wv[d]*Wo[d]; }
  cqk *= 0.25f;
  float xr[10];
  #pragma unroll
  for (int q=0;q<10;q++) xr[q] = x[b*10+q];
  float y[10];
  attn10(xr, cqk, cvo, y);
  #pragma unroll
  for (int q=0;q<10;q++) h[b*10+q] = y[q];
  moments_block(y, red, Pb, t);
}

// fold BN over (10,128) from 512 moment-partials -> WT (128,10), bo (128)
__global__ void k_fold10_part(const float* __restrict__ Pb,
                              const float* __restrict__ W,
                              const float* __restrict__ bv, const float* __restrict__ g,
                              const float* __restrict__ be,
                              float* __restrict__ WT, float* __restrict__ bo){
  __shared__ float sM[65];
  int t = threadIdx.x;
  if (t < 65){
    float acc = 0.f;
    for (int gg=0; gg<512; gg++) acc += Pb[(size_t)gg*65 + t];
    sM[t] = acc;
  }
  __syncthreads();
  int j = t;
  if (j >= 128) return;
  const float invB = 1.f/(float)BN;
  float Eh[10];
  #pragma unroll
  for (int i=0;i<10;i++) Eh[i] = sM[i]*invB;
  float wj[10];
  #pragma unroll
  for (int i=0;i<10;i++) wj[i] = W[i*128+j];
  float mu = bv[j];
  #pragma unroll
  for (int i=0;i<10;i++) mu += Eh[i]*wj[i];
  float var = 0.f;
  #pragma unroll
  for (int i=0;i<10;i++){
    #pragma unroll
    for (int l=0;l<10;l++){
      int a = i<l ? i : l, c = i<l ? l : i;
      int id = 10*a - a*(a-1)/2 + (c-a);
      float cov = sM[10+id]*invB - Eh[i]*Eh[l];
      var += wj[i]*wj[l]*cov;
    }
  }
  float s = g[j]*rsqrtf(var + EPS);
  #pragma unroll
  for (int i=0;i<10;i++) WT[j*10+i] = wj[i]*s;
  bo[j] = (bv[j]-mu)*s + be[j];
}

// legacy atomic-M fold (fallback path only)
__global__ void k_fold10_atomic(const float* __restrict__ M,
                                const float* __restrict__ W,
                                const float* __restrict__ bv, const float* __restrict__ g,
                                const float* __restrict__ be,
                                float* __restrict__ WT, float* __restrict__ bo){
  int j = threadIdx.x;
  if (j >= 128) return;
  const float invB = 1.f/(float)BN;
  float Eh[10];
  #pragma unroll
  for (int i=0;i<10;i++) Eh[i] = M[i]*invB;
  float wj[10];
  #pragma unroll
  for (int i=0;i<10;i++) wj[i] = W[i*128+j];
  float mu = bv[j];
  #pragma unroll
  for (int i=0;i<10;i++) mu += Eh[i]*wj[i];
  float var = 0.f;
  #pragma unroll
  for (int i=0;i<10;i++){
    #pragma unroll
    for (int l=0;l<10;l++){
      int a = i<l ? i : l, c = i<l ? l : i;
      int id = 10*a - a*(a-1)/2 + (c-a);
      float cov = M[10+id]*invB - Eh[i]*Eh[l];
      var += wj[i]*wj[l]*cov;
    }
  }
  float s = g[j]*rsqrtf(var + EPS);
  #pragma unroll
  for (int i=0;i<10;i++) WT[j*10+i] = wj[i]*s;
  bo[j] = (bv[j]-mu)*s + be[j];
}

// BN fold as per-column affine from NBKT bucket stats
__global__ void k_fold_affine(const float* __restrict__ stats,
                              const float* __restrict__ g,
                              const float* __restrict__ be,
                              float* __restrict__ s, float* __restrict__ tt){
  int j = threadIdx.x;
  if (j >= 256) return;
  float su = 0.f, sq = 0.f;
  #pragma unroll 4
  for (int k=0;k<NBKT;k++){
    su += stats[k*512 + j];
    sq += stats[k*512 + 256 + j];
  }
  const float invB = 1.f/(float)BN;
  float mu  = su*invB;
  float var = sq*invB - mu*mu;
  float sc = g[j]*rsqrtf(var + EPS);
  s[j]  = sc;
  tt[j] = be[j] - mu*sc;
}

// ===================== fast path =====================
// fused 10 -> relu(BN-folded 128) -> 256 GEMM; writes z (bf16) + bucketed stats
__global__ __launch_bounds__(256) void k_layer_big(
    const float* __restrict__ h,      // (B,10)
    const float* __restrict__ WaT,    // (128,10) folded
    const float* __restrict__ ba,     // (128)
    const float* __restrict__ Wb,     // (128,256) RAW (z is pre-BN)
    const float* __restrict__ bb,     // (256)
    unsigned short* __restrict__ z,   // (B,256) bf16 out
    float* __restrict__ stats)        // NBKT x 512: sum | sumsq
{
  __shared__ float h1T[128][68];
  __shared__ float hs[64][10];
  __shared__ float sWaT[1280];
  __shared__ float sstats[512];
  int t = threadIdx.x;
  size_t row0 = (size_t)blockIdx.x * 64;

  for (int idx = t; idx < 640; idx += 256) hs[idx/10][idx%10] = h[row0*10 + idx];
  for (int idx = t; idx < 1280; idx += 256) sWaT[idx] = WaT[idx];
  sstats[t] = 0.f; sstats[256+t] = 0.f;
  __syncthreads();

  // phase 1: h1 = relu(h @ WaT' + ba), 32 values per thread
  {
    int r  = t & 63;
    int i0 = (t >> 6) * 32;
    float hr[10];
    #pragma unroll
    for (int l=0;l<10;l++) hr[l] = hs[r][l];
    for (int k=0;k<32;k++){
      int i = i0 + k;
      float v = ba[i];
      #pragma unroll
      for (int l=0;l<10;l++) v = fmaf(hr[l], sWaT[i*10+l], v);
      h1T[i][r] = fmaxf(v, 0.f);
    }
  }
  __syncthreads();

  // phase 2: z = h1 @ Wb + bb ; 4 rows x 16 cols per thread
  int tx = t & 15;
  int ty = t >> 4;
  float acc[4][16];
  #pragma unroll
  for (int r=0;r<4;r++)
    #pragma unroll
    for (int c=0;c<16;c++) acc[r][c] = 0.f;

  const float* __restrict__ wrow = Wb + tx*16;
  for (int i=0;i<128;i++){
    const float4* wp = (const float4*)(wrow + (size_t)i*256);
    float wv[16];
    #pragma unroll
    for (int q=0;q<4;q++){
      float4 w = wp[q];
      wv[4*q+0]=w.x; wv[4*q+1]=w.y; wv[4*q+2]=w.z; wv[4*q+3]=w.w;
    }
    float4 av = *(const float4*)&h1T[i][ty*4];
    float a4[4] = {av.x, av.y, av.z, av.w};
    #pragma unroll
    for (int r=0;r<4;r++)
      #pragma unroll
      for (int c=0;c<16;c++)
        acc[r][c] = fmaf(a4[r], wv[c], acc[r][c]);
  }

  // epilogue: +bias, store bf16 z, stats
  #pragma unroll
  for (int r=0;r<4;r++){
    unsigned p[8];
    #pragma unroll
    for (int q=0;q<8;q++){
      float z0 = acc[r][2*q]   + bb[tx*16 + 2*q];
      float z1 = acc[r][2*q+1] + bb[tx*16 + 2*q+1];
      acc[r][2*q]   = z0;
      acc[r][2*q+1] = z1;
      p[q] = pk_bf16(z0, z1);
    }
    uint4* zp = (uint4*)(z + (row0 + ty*4 + r)*256 + tx*16);
    zp[0] = make_uint4(p[0],p[1],p[2],p[3]);
    zp[1] = make_uint4(p[4],p[5],p[6],p[7]);
  }
  int lane = t & 63;
  #pragma unroll
  for (int c=0;c<16;c++){
    float s1 = acc[0][c]+acc[1][c]+acc[2][c]+acc[3][c];
    float q1 = acc[0][c]*acc[0][c]+acc[1][c]*acc[1][c]
             + acc[2][c]*acc[2][c]+acc[3][c]*acc[3][c];
    s1 += __shfl_down(s1, 32); s1 += __shfl_down(s1, 16);
    q1 += __shfl_down(q1, 32); q1 += __shfl_down(q1, 16);
    if (lane < 16){
      atomicAdd(&sstats[tx*16+c], s1);
      atomicAdd(&sstats[256+tx*16+c], q1);
    }
  }
  __syncthreads();
  int bkt = blockIdx.x & (NBKT-1);
  atomicAdd(&stats[bkt*512 + t], sstats[t]);
  atomicAdd(&stats[bkt*512 + 256 + t], sstats[256+t]);
}

// consume z1: h2 = relu(s*z+t) -> z3 = h2 @ Wc(256,10) + bc -> attn2 -> hh, partials
__global__ __launch_bounds__(256) void k_consume_mid(
    const unsigned short* __restrict__ z,
    const float* __restrict__ s_g, const float* __restrict__ t_g,
    const float* __restrict__ Wc,  const float* __restrict__ bc,
    const float* __restrict__ Wq, const float* __restrict__ Wk,
    const float* __restrict__ Wv, const float* __restrict__ Wo,
    float* __restrict__ hh, float* __restrict__ Pb){
  __shared__ float sW[2560];
  __shared__ float ss[256], st[256];
  __shared__ float red[4][65];
  int t = threadIdx.x;
  for (int idx=t; idx<2560; idx+=256) sW[idx] = Wc[idx];
  ss[t] = s_g[t]; st[t] = t_g[t];
  __syncthreads();
  size_t b = (size_t)blockIdx.x*256 + t;
  float z3[10];
  #pragma unroll
  for (int l=0;l<10;l++) z3[l] = bc[l];
  const uint4* zr = (const uint4*)(z + b*256);
  for (int v=0; v<32; v++){
    uint4 pkt = zr[v];
    unsigned w4[4] = {pkt.x, pkt.y, pkt.z, pkt.w};
    #pragma unroll
    for (int q=0;q<4;q++){
      int j = v*8 + q*2;
      float f0 = __uint_as_float(w4[q] << 16);
      float f1 = __uint_as_float(w4[q] & 0xffff0000u);
      float h20 = fmaxf(fmaf(ss[j],   f0, st[j]),   0.f);
      float h21 = fmaxf(fmaf(ss[j+1], f1, st[j+1]), 0.f);
      #pragma unroll
      for (int l=0;l<10;l++) z3[l] = fmaf(h20, sW[j*10+l], z3[l]);
      #pragma unroll
      for (int l=0;l<10;l++) z3[l] = fmaf(h21, sW[(j+1)*10+l], z3[l]);
    }
  }
  float cqk=0.f, cvo=0.f;
  #pragma unroll
  for (int d=0;d<16;d++){ cqk += Wq[d]*Wk[d]; cvo += Wv[d]*Wo[d]; }
  cqk *= 0.25f;
  float y[10];
  attn10(z3, cqk, cvo, y);
  #pragma unroll
  for (int q=0;q<10;q++) hh[b*10+q] = y[q];
  moments_block(y, red, Pb, t);
}

// consume z2: h5 = relu(s*z+t) -> out = h5 @ Wc(256,2) + bc
__global__ __launch_bounds__(256) void k_consume_out(
    const unsigned short* __restrict__ z,
    const float* __restrict__ s_g, const float* __restrict__ t_g,
    const float* __restrict__ Wc,  const float* __restrict__ bc,
    float* __restrict__ out){
  __shared__ float sW0[256], sW1[256], ss[256], st[256];
  int t = threadIdx.x;
  sW0[t] = Wc[t*2]; sW1[t] = Wc[t*2+1];
  ss[t] = s_g[t]; st[t] = t_g[t];
  __syncthreads();
  size_t b = (size_t)blockIdx.x*256 + t;
  float o0 = bc[0], o1 = bc[1];
  const uint4* zr = (const uint4*)(z + b*256);
  for (int v=0; v<32; v++){
    uint4 pkt = zr[v];
    unsigned w4[4] = {pkt.x, pkt.y, pkt.z, pkt.w};
    #pragma unroll
    for (int q=0;q<4;q++){
      int j = v*8 + q*2;
      float f0 = __uint_as_float(w4[q] << 16);
      float f1 = __uint_as_float(w4[q] & 0xffff0000u);
      float h20 = fmaxf(fmaf(ss[j],   f0, st[j]),   0.f);
      float h21 = fmaxf(fmaf(ss[j+1], f1, st[j+1]), 0.f);
      o0 = fmaf(h20, sW0[j],   o0); o1 = fmaf(h20, sW1[j],   o1);
      o0 = fmaf(h21, sW0[j+1], o0); o1 = fmaf(h21, sW1[j+1], o1);
    }
  }
  out[b*2]   = o0;
  out[b*2+1] = o1;
}

// ===================== fallback path (verified round-0 style) =====================
__global__ void k_fold_big(const float* __restrict__ stats,
                           const float* __restrict__ W,
                           const float* __restrict__ bv, const float* __restrict__ g,
                           const float* __restrict__ be,
                           float* __restrict__ Wf, float* __restrict__ bf){
  int j = blockIdx.x*256 + threadIdx.x;
  if (j >= 256) return;
  const float invB = 1.f/(float)BN;
  float mu  = stats[j]*invB;
  float var = stats[256+j]*invB - mu*mu;
  float s = g[j]*rsqrtf(var + EPS);
  bf[j] = (bv[j]-mu)*s + be[j];
  for (int i=0;i<128;i++) Wf[i*256+j] = W[i*256+j]*s;
}

__global__ __launch_bounds__(256) void k_mid(
    const float* __restrict__ h,
    const float* __restrict__ WaT, const float* __restrict__ ba,
    const float* __restrict__ Wb,  const float* __restrict__ bb,
    float* __restrict__ stats){
  int b = blockIdx.x*256 + threadIdx.x;
  if (b >= BN) return;
  float hr[10];
  #pragma unroll
  for (int l=0;l<10;l++) hr[l] = h[(size_t)b*10+l];
  int lane = threadIdx.x & 63;
  for (int jc=0;jc<4;jc++){
    float acc[64];
    #pragma unroll
    for (int j=0;j<64;j++) acc[j] = bb[jc*64+j];
    for (int i=0;i<128;i++){
      float h1 = ba[i];
      #pragma unroll
      for (int l=0;l<10;l++) h1 += hr[l]*WaT[i*10+l];
      h1 = fmaxf(h1, 0.f);
      const float* __restrict__ w = &Wb[i*256 + jc*64];
      #pragma unroll
      for (int j=0;j<64;j++) acc[j] += h1*w[j];
    }
    #pragma unroll
    for (int j=0;j<64;j++){
      float s1 = wsum(acc[j]);
      float s2 = wsum(acc[j]*acc[j]);
      if (lane==0){
        atomicAdd(&stats[jc*64+j], s1);
        atomicAdd(&stats[256+jc*64+j], s2);
      }
    }
  }
}

__global__ __launch_bounds__(256) void k_mid2(
    const float* __restrict__ h,
    const float* __restrict__ WaT, const float* __restrict__ ba,
    const float* __restrict__ Wbf, const float* __restrict__ bbf,
    const float* __restrict__ Wc,  const float* __restrict__ bc,
    const float* __restrict__ Wq, const float* __restrict__ Wk,
    const float* __restrict__ Wv, const float* __restrict__ Wo,
    float* __restrict__ hh, float* __restrict__ M){
  int b = blockIdx.x*256 + threadIdx.x;
  if (b >= BN) return;
  float hr[10];
  #pragma unroll
  for (int l=0;l<10;l++) hr[l] = h[(size_t)b*10+l];
  float z3[10];
  #pragma unroll
  for (int l=0;l<10;l++) z3[l] = bc[l];
  for (int jc=0;jc<4;jc++){
    float acc[64];
    #pragma unroll
    for (int j=0;j<64;j++) acc[j] = bbf[jc*64+j];
    for (int i=0;i<128;i++){
      float h1 = ba[i];
      #pragma unroll
      for (int l=0;l<10;l++) h1 += hr[l]*WaT[i*10+l];
      h1 = fmaxf(h1, 0.f);
      const float* __restrict__ w = &Wbf[i*256 + jc*64];
      #pragma unroll
      for (int j=0;j<64;j++) acc[j] += h1*w[j];
    }
    #pragma unroll
    for (int j=0;j<64;j++){
      float h2 = fmaxf(acc[j], 0.f);
      const float* __restrict__ wc = &Wc[(jc*64+j)*10];
      #pragma unroll
      for (int l=0;l<10;l++) z3[l] += h2*wc[l];
    }
  }
  float cqk=0.f, cvo=0.f;
  #pragma unroll
  for (int d=0;d<16;d++){ cqk += Wq[d]*Wk[d]; cvo += Wv[d]*Wo[d]; }
  cqk *= 0.25f;
  float y[10];
  attn10(z3, cqk, cvo, y);
  #pragma unroll
  for (int q=0;q<10;q++) hh[(size_t)b*10+q] = y[q];
  moments10(y, M, threadIdx.x & 63);
}

__global__ __launch_bounds__(256) void k_out(
    const float* __restrict__ h,
    const float* __restrict__ WaT, const float* __restrict__ ba,
    const float* __restrict__ Wbf, const float* __restrict__ bbf,
    const float* __restrict__ Wc,  const float* __restrict__ bc,
    float* __restrict__ out){
  int b = blockIdx.x*256 + threadIdx.x;
  if (b >= BN) return;
  float hr[10];
  #pragma unroll
  for (int l=0;l<10;l++) hr[l] = h[(size_t)b*10+l];
  float o0 = bc[0], o1 = bc[1];
  for (int jc=0;jc<4;jc++){
    float acc[64];
    #pragma unroll
    for (int j=0;j<64;j++) acc[j] = bbf[jc*64+j];
    for (int i=0;i<128;i++){
      float h4 = ba[i];
      #pragma unroll
      for (int l=0;l<10;l++) h4 += hr[l]*WaT[i*10+l];
      h4 = fmaxf(h4, 0.f);
      const float* __restrict__ w = &Wbf[i*256 + jc*64];
      #pragma unroll
      for (int j=0;j<64;j++) acc[j] += h4*w[j];
    }
    #pragma unroll
    for (int j=0;j<64;j++){
      float h5 = fmaxf(acc[j], 0.f);
      o0 += h5*Wc[(jc*64+j)*2];
      o1 += h5*Wc[(jc*64+j)*2+1];
    }
  }
  out[(size_t)b*2]   = o0;
  out[(size_t)b*2+1] = o1;
}

extern "C" void kernel_launch(void* const* d_in, const int* in_sizes, int n_in,
                              void* d_out, int out_size, void* d_ws, size_t ws_size,
                              hipStream_t stream){
  const float* x   = (const float*)d_in[0];
  const float* Wq1 = (const float*)d_in[1];
  const float* Wk1 = (const float*)d_in[2];
  const float* Wv1 = (const float*)d_in[3];
  const float* Wo1 = (const float*)d_in[4];
  const float* Wq2 = (const float*)d_in[5];
  const float* Wk2 = (const float*)d_in[6];
  const float* Wv2 = (const float*)d_in[7];
  const float* Wo2 = (const float*)d_in[8];
  const float* W1a = (const float*)d_in[9];  const float* b1a = (const float*)d_in[10];
  const float* g1a = (const float*)d_in[11]; const float* be1a= (const float*)d_in[12];
  const float* W1b = (const float*)d_in[13]; const float* b1b = (const float*)d_in[14];
  const float* g1b = (const float*)d_in[15]; const float* be1b= (const float*)d_in[16];
  const float* W1c = (const float*)d_in[17]; const float* b1c = (const float*)d_in[18];
  const float* W2a = (const float*)d_in[19]; const float* b2a = (const float*)d_in[20];
  const float* g2a = (const float*)d_in[21]; const float* be2a= (const float*)d_in[22];
  const float* W2b = (const float*)d_in[23]; const float* b2b = (const float*)d_in[24];
  const float* g2b = (const float*)d_in[25]; const float* be2b= (const float*)d_in[26];
  const float* W2c = (const float*)d_in[27]; const float* b2c = (const float*)d_in[28];

  float* f   = (float*)d_ws;
  float* h   = f + OFF_H;
  float* hh  = f + OFF_HH;
  float* M1  = f + OFF_M1;
  float* S2  = f + OFF_S2;
  float* M3  = f + OFF_M3;
  float* S4  = f + OFF_S4;
  float* WA1 = f + OFF_WA1; float* BA1 = f + OFF_BA1;
  float* WA2 = f + OFF_WA2; float* BA2 = f + OFF_BA2;
  float* SC2 = f + OFF_SC2; float* TC2 = f + OFF_TC2;
  float* SC4 = f + OFF_SC4; float* TC4 = f + OFF_TC4;
  float* WB1 = f + OFF_WB1; float* BB1 = f + OFF_BB1;
  float* WB2 = f + OFF_WB2; float* BB2 = f + OFF_BB2;
  float* P1  = f + OFF_P1;  float* P3  = f + OFF_P3;
  float* S2B = f + OFF_S2B; float* S4B = f + OFF_S4B;
  unsigned short* Z = (unsigned short*)((char*)d_ws + OFF_Z_BYTES);

  dim3 grid(BN/256), blk(256);

  if (ws_size >= WS_NEED){
    hipMemsetAsync(S2B, 0, (size_t)2*NBKT*512*sizeof(float), stream);
    dim3 gbig(BN/64);
    k_attn_in<<<grid,blk,0,stream>>>(x, Wq1,Wk1,Wv1,Wo1, h, P1);
    k_fold10_part<<<1,128,0,stream>>>(P1, W1a,b1a,g1a,be1a, WA1,BA1);
    k_layer_big<<<gbig,blk,0,stream>>>(h, WA1,BA1, W1b,b1b, Z, S2B);
    k_fold_affine<<<1,256,0,stream>>>(S2B, g1b, be1b, SC2, TC2);
    k_consume_mid<<<grid,blk,0,stream>>>(Z, SC2,TC2, W1c,b1c, Wq2,Wk2,Wv2,Wo2, hh, P3);
    k_fold10_part<<<1,128,0,stream>>>(P3, W2a,b2a,g2a,be2a, WA2,BA2);
    k_layer_big<<<gbig,blk,0,stream>>>(hh, WA2,BA2, W2b,b2b, Z, S4B);
    k_fold_affine<<<1,256,0,stream>>>(S4B, g2b, be2b, SC4, TC4);
    k_consume_out<<<grid,blk,0,stream>>>(Z, SC4,TC4, W2c,b2c, (float*)d_out);
  } else {
    hipMemsetAsync(M1, 0, (65+512+65+512)*sizeof(float), stream);
    k_attn_in<<<grid,blk,0,stream>>>(x, Wq1,Wk1,Wv1,Wo1, h, P1);
    k_fold10_part<<<1,128,0,stream>>>(P1, W1a,b1a,g1a,be1a, WA1,BA1);
    k_mid<<<grid,blk,0,stream>>>(h, WA1,BA1, W1b,b1b, S2);
    k_fold_big<<<1,256,0,stream>>>(S2, W1b,b1b,g1b,be1b, WB1,BB1);
    k_mid2<<<grid,blk,0,stream>>>(h, WA1,BA1, WB1,BB1, W1c,b1c, Wq2,Wk2,Wv2,Wo2, hh, M3);
    k_fold10_atomic<<<1,128,0,stream>>>(M3, W2a,b2a,g2a,be2a, WA2,BA2);
    k_mid<<<grid,blk,0,stream>>>(hh, WA2,BA2, W2b,b2b, S4);
    k_fold_big<<<1,256,0,stream>>>(S4, W2b,b2b,g2b,be2b, WB2,BB2);
    k_out<<<grid,blk,0,stream>>>(hh, WA2,BA2, WB2,BB2, W2c,b2c, (float*)d_out);
  }
}

// Round 4
// 225.891 us; speedup vs baseline: 24.7214x; 3.1085x over previous
//
#include <hip/hip_runtime.h>
#include <hip/hip_bf16.h>

#define EPS 1e-5f
constexpr int BN = 131072;
constexpr int NBKT = 32;

typedef __attribute__((ext_vector_type(8))) short bf16x8;
typedef __attribute__((ext_vector_type(4))) float f32x4;

// ---- workspace layout (float offsets) ----
constexpr size_t OFF_H   = 0;                         // (B,10) attn1 out
constexpr size_t OFF_HH  = OFF_H  + (size_t)BN*10;    // (B,10) attn2 out
constexpr size_t OFF_M1  = OFF_HH + (size_t)BN*10;    // 65  (fallback)
constexpr size_t OFF_S2  = OFF_M1 + 65;               // 512 (fallback)
constexpr size_t OFF_M3  = OFF_S2 + 512;              // 65  (fallback)
constexpr size_t OFF_S4  = OFF_M3 + 65;               // 512 (fallback)
constexpr size_t OFF_WA1 = OFF_S4 + 512;              // 128x10 folded BN1 (T)
constexpr size_t OFF_BA1 = OFF_WA1 + 1280;            // 128
constexpr size_t OFF_WA2 = OFF_BA1 + 128;             // 128x10 folded BN3 (T)
constexpr size_t OFF_BA2 = OFF_WA2 + 1280;            // 128
constexpr size_t OFF_SC2 = OFF_BA2 + 128;             // 256
constexpr size_t OFF_TC2 = OFF_SC2 + 256;             // 256
constexpr size_t OFF_SC4 = OFF_TC2 + 256;             // 256
constexpr size_t OFF_TC4 = OFF_SC4 + 256;             // 256
constexpr size_t OFF_WB1 = OFF_TC4 + 256;             // 128x256 (fallback)
constexpr size_t OFF_BB1 = OFF_WB1 + 32768;           // 256
constexpr size_t OFF_WB2 = OFF_BB1 + 256;             // 128x256 (fallback)
constexpr size_t OFF_BB2 = OFF_WB2 + 32768;           // 256
constexpr size_t OFF_P1  = OFF_BB2 + 256;             // 512x65 moment partials
constexpr size_t OFF_P3  = OFF_P1 + 512*65;           // 512x65
constexpr size_t OFF_S2B = OFF_P3 + 512*65;           // NBKT x 512 bucket stats L1
constexpr size_t OFF_S4B = OFF_S2B + (size_t)NBKT*512;// NBKT x 512 bucket stats L2
constexpr size_t OFF_WT1 = OFF_S4B + (size_t)NBKT*512;// 256x128 bf16 (as 16384 floats)
constexpr size_t OFF_WT2 = OFF_WT1 + 16384;
constexpr size_t OFF_END = OFF_WT2 + 16384;
constexpr size_t OFF_Z_BYTES = ((OFF_END*4 + 255) & ~(size_t)255); // bf16 z buffer
constexpr size_t WS_NEED_OLD  = OFF_Z_BYTES + (size_t)BN*256*2;
constexpr size_t WS_NEED_MFMA = WS_NEED_OLD;  // WT buffers included in OFF_END

__device__ __forceinline__ float wsum(float v){
  v += __shfl_down(v, 32);
  v += __shfl_down(v, 16);
  v += __shfl_down(v, 8);
  v += __shfl_down(v, 4);
  v += __shfl_down(v, 2);
  v += __shfl_down(v, 1);
  return v;
}

__device__ __forceinline__ unsigned pk_bf16(float a, float b){
  union { __hip_bfloat16 h[2]; unsigned u; } cv;
  cv.h[0] = __float2bfloat16(a);
  cv.h[1] = __float2bfloat16(b);
  return cv.u;
}

__device__ __forceinline__ unsigned short bf16_1(float a){
  union { __hip_bfloat16 h; unsigned short u; } cv;
  cv.h = __float2bfloat16(a);
  return cv.u;
}

// attention on a 10-vector: softmax over q (axis=1!) per column k
__device__ __forceinline__ void attn10(const float* xr, float cqk, float cvo, float* y){
  #pragma unroll
  for (int q=0;q<10;q++) y[q] = 0.f;
  #pragma unroll
  for (int k=0;k<10;k++){
    float t = cqk * xr[k];
    float m = t*xr[0];
    #pragma unroll
    for (int q=1;q<10;q++) m = fmaxf(m, t*xr[q]);
    float ex[10]; float s = 0.f;
    #pragma unroll
    for (int q=0;q<10;q++){ ex[q] = __expf(t*xr[q]-m); s += ex[q]; }
    float f = xr[k]/s;
    #pragma unroll
    for (int q=0;q<10;q++) y[q] += ex[q]*f;
  }
  #pragma unroll
  for (int q=0;q<10;q++) y[q] *= cvo;
}

// block-level moment reduction: 65 wave-reduces -> LDS -> one partial row per block
__device__ __forceinline__ void moments_block(const float* y, float (*red)[65],
                                              float* Pb, int t){
  int lane = t & 63, w = t >> 6;
  #pragma unroll
  for (int i=0;i<10;i++){
    float v = wsum(y[i]);
    if (lane==0) red[w][i] = v;
  }
  #pragma unroll
  for (int i=0;i<10;i++){
    #pragma unroll
    for (int j=i;j<10;j++){
      float v = wsum(y[i]*y[j]);
      if (lane==0) red[w][10 + 10*i - i*(i-1)/2 + (j-i)] = v;
    }
  }
  __syncthreads();
  if (t < 65)
    Pb[(size_t)blockIdx.x*65 + t] = red[0][t]+red[1][t]+red[2][t]+red[3][t];
}

// legacy atomic moments (fallback path only)
__device__ __forceinline__ void moments10(const float* y, float* M, int lane){
  #pragma unroll
  for (int i=0;i<10;i++){
    float s = wsum(y[i]);
    if (lane==0) atomicAdd(&M[i], s);
  }
  #pragma unroll
  for (int i=0;i<10;i++){
    #pragma unroll
    for (int j=i;j<10;j++){
      int id = 10*i - i*(i-1)/2 + (j-i);
      float s = wsum(y[i]*y[j]);
      if (lane==0) atomicAdd(&M[10+id], s);
    }
  }
}

// K1: x -> attn1 -> h  (+ per-block moment partials)
__global__ __launch_bounds__(256) void k_attn_in(
    const float* __restrict__ x,
    const float* __restrict__ Wq, const float* __restrict__ Wk,
    const float* __restrict__ Wv, const float* __restrict__ Wo,
    float* __restrict__ h, float* __restrict__ Pb){
  __shared__ float red[4][65];
  int t = threadIdx.x;
  size_t b = (size_t)blockIdx.x*256 + t;
  float cqk=0.f, cvo=0.f;
  #pragma unroll
  for (int d=0;d<16;d++){ cqk += Wq[d]*Wk[d]; cvo += Wv[d]*Wo[d]; }
  cqk *= 0.25f;
  float xr[10];
  #pragma unroll
  for (int q=0;q<10;q++) xr[q] = x[b*10+q];
  float y[10];
  attn10(xr, cqk, cvo, y);
  #pragma unroll
  for (int q=0;q<10;q++) h[b*10+q] = y[q];
  moments_block(y, red, Pb, t);
}

// fold BN over (10,128) from 512 moment-partials -> WT (128,10), bo (128)
__global__ void k_fold10_part(const float* __restrict__ Pb,
                              const float* __restrict__ W,
                              const float* __restrict__ bv, const float* __restrict__ g,
                              const float* __restrict__ be,
                              float* __restrict__ WT, float* __restrict__ bo){
  __shared__ float sM[65];
  int t = threadIdx.x;
  if (t < 65){
    float acc = 0.f;
    for (int gg=0; gg<512; gg++) acc += Pb[(size_t)gg*65 + t];
    sM[t] = acc;
  }
  __syncthreads();
  int j = t;
  if (j >= 128) return;
  const float invB = 1.f/(float)BN;
  float Eh[10];
  #pragma unroll
  for (int i=0;i<10;i++) Eh[i] = sM[i]*invB;
  float wj[10];
  #pragma unroll
  for (int i=0;i<10;i++) wj[i] = W[i*128+j];
  float mu = bv[j];
  #pragma unroll
  for (int i=0;i<10;i++) mu += Eh[i]*wj[i];
  float var = 0.f;
  #pragma unroll
  for (int i=0;i<10;i++){
    #pragma unroll
    for (int l=0;l<10;l++){
      int a = i<l ? i : l, c = i<l ? l : i;
      int id = 10*a - a*(a-1)/2 + (c-a);
      float cov = sM[10+id]*invB - Eh[i]*Eh[l];
      var += wj[i]*wj[l]*cov;
    }
  }
  float s = g[j]*rsqrtf(var + EPS);
  #pragma unroll
  for (int i=0;i<10;i++) WT[j*10+i] = wj[i]*s;
  bo[j] = (bv[j]-mu)*s + be[j];
}

// legacy atomic-M fold (fallback path only)
__global__ void k_fold10_atomic(const float* __restrict__ M,
                                const float* __restrict__ W,
                                const float* __restrict__ bv, const float* __restrict__ g,
                                const float* __restrict__ be,
                                float* __restrict__ WT, float* __restrict__ bo){
  int j = threadIdx.x;
  if (j >= 128) return;
  const float invB = 1.f/(float)BN;
  float Eh[10];
  #pragma unroll
  for (int i=0;i<10;i++) Eh[i] = M[i]*invB;
  float wj[10];
  #pragma unroll
  for (int i=0;i<10;i++) wj[i] = W[i*128+j];
  float mu = bv[j];
  #pragma unroll
  for (int i=0;i<10;i++) mu += Eh[i]*wj[i];
  float var = 0.f;
  #pragma unroll
  for (int i=0;i<10;i++){
    #pragma unroll
    for (int l=0;l<10;l++){
      int a = i<l ? i : l, c = i<l ? l : i;
      int id = 10*a - a*(a-1)/2 + (c-a);
      float cov = M[10+id]*invB - Eh[i]*Eh[l];
      var += wj[i]*wj[l]*cov;
    }
  }
  float s = g[j]*rsqrtf(var + EPS);
  #pragma unroll
  for (int i=0;i<10;i++) WT[j*10+i] = wj[i]*s;
  bo[j] = (bv[j]-mu)*s + be[j];
}

// BN fold as per-column affine from NBKT bucket stats
__global__ void k_fold_affine(const float* __restrict__ stats,
                              const float* __restrict__ g,
                              const float* __restrict__ be,
                              float* __restrict__ s, float* __restrict__ tt){
  int j = threadIdx.x;
  if (j >= 256) return;
  float su = 0.f, sq = 0.f;
  #pragma unroll 4
  for (int k=0;k<NBKT;k++){
    su += stats[k*512 + j];
    sq += stats[k*512 + 256 + j];
  }
  const float invB = 1.f/(float)BN;
  float mu  = su*invB;
  float var = sq*invB - mu*mu;
  float sc = g[j]*rsqrtf(var + EPS);
  s[j]  = sc;
  tt[j] = be[j] - mu*sc;
}

// transpose+convert W (128,256) f32 -> WT (256,128) bf16
__global__ __launch_bounds__(256) void k_prep_wt(const float* __restrict__ W,
                                                 unsigned short* __restrict__ WT){
  int idx = blockIdx.x*256 + threadIdx.x;   // < 32768
  int c = idx >> 7, k = idx & 127;
  WT[idx] = bf16_1(W[k*256 + c]);
}

// ===================== MFMA fast path =====================
// fused 10 -> relu(BN-folded 128) -> 256 GEMM via mfma_f32_16x16x32_bf16
// block: 256 thr (4 waves), 64 rows. wave w owns cols [w*64, w*64+64).
__global__ __launch_bounds__(256) void k_layer_mfma(
    const float* __restrict__ h,            // (B,10)
    const float* __restrict__ WaT,          // (128,10) folded
    const float* __restrict__ ba,           // (128)
    const unsigned short* __restrict__ WT,  // (256,128) bf16  (W transposed)
    const float* __restrict__ bb,           // (256)
    unsigned short* __restrict__ z,         // (B,256) bf16 out
    float* __restrict__ stats)              // NBKT x 512: sum | sumsq
{
  __shared__ unsigned short h1s[64*128];    // 16 KB, XOR-swizzled rows
  __shared__ float hs[64][10];
  __shared__ float sWaT[1280];
  __shared__ float sstats[512];
  int t = threadIdx.x;
  int lane = t & 63, w = t >> 6;
  int ci = lane & 15, g = lane >> 4;
  size_t row0 = (size_t)blockIdx.x * 64;

  // B fragments: loaded once from L2. b[nt][kt]: col = w*64+nt*16+ci, k = kt*32+g*8..+7
  bf16x8 bfr[4][4];
  #pragma unroll
  for (int nt=0; nt<4; nt++)
    #pragma unroll
    for (int kt=0; kt<4; kt++){
      union { uint4 u; bf16x8 v; } cv;
      cv.u = *(const uint4*)(WT + (size_t)(w*64 + nt*16 + ci)*128 + kt*32 + g*8);
      bfr[nt][kt] = cv.v;
    }

  for (int idx = t; idx < 640; idx += 256) hs[idx/10][idx%10] = h[row0*10 + idx];
  for (int idx = t; idx < 1280; idx += 256) sWaT[idx] = WaT[idx];
  __syncthreads();

  // phase 1: h1 = relu(h @ WaT' + ba) -> bf16 swizzled LDS [64][128]
  {
    int r = lane;
    int i0 = w * 32;
    float hr[10];
    #pragma unroll
    for (int l=0;l<10;l++) hr[l] = hs[r][l];
    #pragma unroll
    for (int j=0;j<4;j++){
      unsigned pk[4];
      #pragma unroll
      for (int q=0;q<4;q++){
        int i = i0 + j*8 + q*2;
        float v0 = ba[i], v1 = ba[i+1];
        #pragma unroll
        for (int l=0;l<10;l++){
          v0 = fmaf(hr[l], sWaT[i*10+l],     v0);
          v1 = fmaf(hr[l], sWaT[(i+1)*10+l], v1);
        }
        pk[q] = pk_bf16(fmaxf(v0,0.f), fmaxf(v1,0.f));
      }
      int byte = r*256 + (((i0 + j*8)*2) ^ ((r&7)<<4));
      *(uint4*)((char*)h1s + byte) = make_uint4(pk[0],pk[1],pk[2],pk[3]);
    }
  }
  __syncthreads();

  // phase 2: MFMA. acc[mt][nt]: rows mt*16.., cols w*64+nt*16..
  f32x4 acc[4][4];
  #pragma unroll
  for (int mt=0;mt<4;mt++)
    #pragma unroll
    for (int nt=0;nt<4;nt++)
      acc[mt][nt] = (f32x4){0.f,0.f,0.f,0.f};

  #pragma unroll
  for (int mt=0; mt<4; mt++){
    int r = mt*16 + ci;
    bf16x8 af[4];
    #pragma unroll
    for (int kt=0; kt<4; kt++){
      int byte = r*256 + ((kt*64 + g*16) ^ ((r&7)<<4));
      af[kt] = *(const bf16x8*)((const char*)h1s + byte);
    }
    #pragma unroll
    for (int nt=0; nt<4; nt++)
      #pragma unroll
      for (int kt=0; kt<4; kt++)
        acc[mt][nt] = __builtin_amdgcn_mfma_f32_16x16x32_bf16(
            af[kt], bfr[nt][kt], acc[mt][nt], 0, 0, 0);
  }

  // epilogue: +bias, store bf16 z, per-col stats (cols are wave-exclusive)
  float bbv[4];
  #pragma unroll
  for (int nt=0;nt<4;nt++) bbv[nt] = bb[w*64 + nt*16 + ci];
  float csum[4] = {0,0,0,0}, csq[4] = {0,0,0,0};
  #pragma unroll
  for (int mt=0; mt<4; mt++){
    #pragma unroll
    for (int nt=0; nt<4; nt++){
      #pragma unroll
      for (int j=0;j<4;j++){
        float zv = acc[mt][nt][j] + bbv[nt];
        int r = mt*16 + g*4 + j;
        int c = w*64 + nt*16 + ci;
        z[(row0 + r)*256 + c] = bf16_1(zv);
        csum[nt] += zv;
        csq[nt]  += zv*zv;
      }
    }
  }
  #pragma unroll
  for (int nt=0; nt<4; nt++){
    float s1 = csum[nt], s2 = csq[nt];
    s1 += __shfl_down(s1, 32); s1 += __shfl_down(s1, 16);
    s2 += __shfl_down(s2, 32); s2 += __shfl_down(s2, 16);
    if (lane < 16){
      sstats[w*64 + nt*16 + ci]       = s1;
      sstats[256 + w*64 + nt*16 + ci] = s2;
    }
  }
  __syncthreads();
  int bkt = blockIdx.x & (NBKT-1);
  atomicAdd(&stats[bkt*512 + t], sstats[t]);
  atomicAdd(&stats[bkt*512 + 256 + t], sstats[256+t]);
}

// ===================== old fast path (fallback tier) =====================
__global__ __launch_bounds__(256) void k_layer_big(
    const float* __restrict__ h,
    const float* __restrict__ WaT,
    const float* __restrict__ ba,
    const float* __restrict__ Wb,
    const float* __restrict__ bb,
    unsigned short* __restrict__ z,
    float* __restrict__ stats)
{
  __shared__ float h1T[128][68];
  __shared__ float hs[64][10];
  __shared__ float sWaT[1280];
  __shared__ float sstats[512];
  int t = threadIdx.x;
  size_t row0 = (size_t)blockIdx.x * 64;

  for (int idx = t; idx < 640; idx += 256) hs[idx/10][idx%10] = h[row0*10 + idx];
  for (int idx = t; idx < 1280; idx += 256) sWaT[idx] = WaT[idx];
  sstats[t] = 0.f; sstats[256+t] = 0.f;
  __syncthreads();
  {
    int r  = t & 63;
    int i0 = (t >> 6) * 32;
    float hr[10];
    #pragma unroll
    for (int l=0;l<10;l++) hr[l] = hs[r][l];
    for (int k=0;k<32;k++){
      int i = i0 + k;
      float v = ba[i];
      #pragma unroll
      for (int l=0;l<10;l++) v = fmaf(hr[l], sWaT[i*10+l], v);
      h1T[i][r] = fmaxf(v, 0.f);
    }
  }
  __syncthreads();
  int tx = t & 15;
  int ty = t >> 4;
  float acc[4][16];
  #pragma unroll
  for (int r=0;r<4;r++)
    #pragma unroll
    for (int c=0;c<16;c++) acc[r][c] = 0.f;
  const float* __restrict__ wrow = Wb + tx*16;
  for (int i=0;i<128;i++){
    const float4* wp = (const float4*)(wrow + (size_t)i*256);
    float wv[16];
    #pragma unroll
    for (int q=0;q<4;q++){
      float4 w = wp[q];
      wv[4*q+0]=w.x; wv[4*q+1]=w.y; wv[4*q+2]=w.z; wv[4*q+3]=w.w;
    }
    float4 av = *(const float4*)&h1T[i][ty*4];
    float a4[4] = {av.x, av.y, av.z, av.w};
    #pragma unroll
    for (int r=0;r<4;r++)
      #pragma unroll
      for (int c=0;c<16;c++)
        acc[r][c] = fmaf(a4[r], wv[c], acc[r][c]);
  }
  #pragma unroll
  for (int r=0;r<4;r++){
    unsigned p[8];
    #pragma unroll
    for (int q=0;q<8;q++){
      float z0 = acc[r][2*q]   + bb[tx*16 + 2*q];
      float z1 = acc[r][2*q+1] + bb[tx*16 + 2*q+1];
      acc[r][2*q]   = z0;
      acc[r][2*q+1] = z1;
      p[q] = pk_bf16(z0, z1);
    }
    uint4* zp = (uint4*)(z + (row0 + ty*4 + r)*256 + tx*16);
    zp[0] = make_uint4(p[0],p[1],p[2],p[3]);
    zp[1] = make_uint4(p[4],p[5],p[6],p[7]);
  }
  int lane = t & 63;
  #pragma unroll
  for (int c=0;c<16;c++){
    float s1 = acc[0][c]+acc[1][c]+acc[2][c]+acc[3][c];
    float q1 = acc[0][c]*acc[0][c]+acc[1][c]*acc[1][c]
             + acc[2][c]*acc[2][c]+acc[3][c]*acc[3][c];
    s1 += __shfl_down(s1, 32); s1 += __shfl_down(s1, 16);
    q1 += __shfl_down(q1, 32); q1 += __shfl_down(q1, 16);
    if (lane < 16){
      atomicAdd(&sstats[tx*16+c], s1);
      atomicAdd(&sstats[256+tx*16+c], q1);
    }
  }
  __syncthreads();
  int bkt = blockIdx.x & (NBKT-1);
  atomicAdd(&stats[bkt*512 + t], sstats[t]);
  atomicAdd(&stats[bkt*512 + 256 + t], sstats[256+t]);
}

// consume z1: h2 = relu(s*z+t) -> z3 = h2 @ Wc(256,10) + bc -> attn2 -> hh, partials
__global__ __launch_bounds__(256) void k_consume_mid(
    const unsigned short* __restrict__ z,
    const float* __restrict__ s_g, const float* __restrict__ t_g,
    const float* __restrict__ Wc,  const float* __restrict__ bc,
    const float* __restrict__ Wq, const float* __restrict__ Wk,
    const float* __restrict__ Wv, const float* __restrict__ Wo,
    float* __restrict__ hh, float* __restrict__ Pb){
  __shared__ float sW[2560];
  __shared__ float ss[256], st[256];
  __shared__ float red[4][65];
  int t = threadIdx.x;
  for (int idx=t; idx<2560; idx+=256) sW[idx] = Wc[idx];
  ss[t] = s_g[t]; st[t] = t_g[t];
  __syncthreads();
  size_t b = (size_t)blockIdx.x*256 + t;
  float z3[10];
  #pragma unroll
  for (int l=0;l<10;l++) z3[l] = bc[l];
  const uint4* zr = (const uint4*)(z + b*256);
  for (int v=0; v<32; v++){
    uint4 pkt = zr[v];
    unsigned w4[4] = {pkt.x, pkt.y, pkt.z, pkt.w};
    #pragma unroll
    for (int q=0;q<4;q++){
      int j = v*8 + q*2;
      float f0 = __uint_as_float(w4[q] << 16);
      float f1 = __uint_as_float(w4[q] & 0xffff0000u);
      float h20 = fmaxf(fmaf(ss[j],   f0, st[j]),   0.f);
      float h21 = fmaxf(fmaf(ss[j+1], f1, st[j+1]), 0.f);
      #pragma unroll
      for (int l=0;l<10;l++) z3[l] = fmaf(h20, sW[j*10+l], z3[l]);
      #pragma unroll
      for (int l=0;l<10;l++) z3[l] = fmaf(h21, sW[(j+1)*10+l], z3[l]);
    }
  }
  float cqk=0.f, cvo=0.f;
  #pragma unroll
  for (int d=0;d<16;d++){ cqk += Wq[d]*Wk[d]; cvo += Wv[d]*Wo[d]; }
  cqk *= 0.25f;
  float y[10];
  attn10(z3, cqk, cvo, y);
  #pragma unroll
  for (int q=0;q<10;q++) hh[b*10+q] = y[q];
  moments_block(y, red, Pb, t);
}

// consume z2: h5 = relu(s*z+t) -> out = h5 @ Wc(256,2) + bc
__global__ __launch_bounds__(256) void k_consume_out(
    const unsigned short* __restrict__ z,
    const float* __restrict__ s_g, const float* __restrict__ t_g,
    const float* __restrict__ Wc,  const float* __restrict__ bc,
    float* __restrict__ out){
  __shared__ float sW0[256], sW1[256], ss[256], st[256];
  int t = threadIdx.x;
  sW0[t] = Wc[t*2]; sW1[t] = Wc[t*2+1];
  ss[t] = s_g[t]; st[t] = t_g[t];
  __syncthreads();
  size_t b = (size_t)blockIdx.x*256 + t;
  float o0 = bc[0], o1 = bc[1];
  const uint4* zr = (const uint4*)(z + b*256);
  for (int v=0; v<32; v++){
    uint4 pkt = zr[v];
    unsigned w4[4] = {pkt.x, pkt.y, pkt.z, pkt.w};
    #pragma unroll
    for (int q=0;q<4;q++){
      int j = v*8 + q*2;
      float f0 = __uint_as_float(w4[q] << 16);
      float f1 = __uint_as_float(w4[q] & 0xffff0000u);
      float h20 = fmaxf(fmaf(ss[j],   f0, st[j]),   0.f);
      float h21 = fmaxf(fmaf(ss[j+1], f1, st[j+1]), 0.f);
      o0 = fmaf(h20, sW0[j],   o0); o1 = fmaf(h20, sW1[j],   o1);
      o0 = fmaf(h21, sW0[j+1], o0); o1 = fmaf(h21, sW1[j+1], o1);
    }
  }
  out[b*2]   = o0;
  out[b*2+1] = o1;
}

// ===================== slow fallback path (round-0 style) =====================
__global__ void k_fold_big(const float* __restrict__ stats,
                           const float* __restrict__ W,
                           const float* __restrict__ bv, const float* __restrict__ g,
                           const float* __restrict__ be,
                           float* __restrict__ Wf, float* __restrict__ bf){
  int j = blockIdx.x*256 + threadIdx.x;
  if (j >= 256) return;
  const float invB = 1.f/(float)BN;
  float mu  = stats[j]*invB;
  float var = stats[256+j]*invB - mu*mu;
  float s = g[j]*rsqrtf(var + EPS);
  bf[j] = (bv[j]-mu)*s + be[j];
  for (int i=0;i<128;i++) Wf[i*256+j] = W[i*256+j]*s;
}

__global__ __launch_bounds__(256) void k_mid(
    const float* __restrict__ h,
    const float* __restrict__ WaT, const float* __restrict__ ba,
    const float* __restrict__ Wb,  const float* __restrict__ bb,
    float* __restrict__ stats){
  int b = blockIdx.x*256 + threadIdx.x;
  if (b >= BN) return;
  float hr[10];
  #pragma unroll
  for (int l=0;l<10;l++) hr[l] = h[(size_t)b*10+l];
  int lane = threadIdx.x & 63;
  for (int jc=0;jc<4;jc++){
    float acc[64];
    #pragma unroll
    for (int j=0;j<64;j++) acc[j] = bb[jc*64+j];
    for (int i=0;i<128;i++){
      float h1 = ba[i];
      #pragma unroll
      for (int l=0;l<10;l++) h1 += hr[l]*WaT[i*10+l];
      h1 = fmaxf(h1, 0.f);
      const float* __restrict__ w = &Wb[i*256 + jc*64];
      #pragma unroll
      for (int j=0;j<64;j++) acc[j] += h1*w[j];
    }
    #pragma unroll
    for (int j=0;j<64;j++){
      float s1 = wsum(acc[j]);
      float s2 = wsum(acc[j]*acc[j]);
      if (lane==0){
        atomicAdd(&stats[jc*64+j], s1);
        atomicAdd(&stats[256+jc*64+j], s2);
      }
    }
  }
}

__global__ __launch_bounds__(256) void k_mid2(
    const float* __restrict__ h,
    const float* __restrict__ WaT, const float* __restrict__ ba,
    const float* __restrict__ Wbf, const float* __restrict__ bbf,
    const float* __restrict__ Wc,  const float* __restrict__ bc,
    const float* __restrict__ Wq, const float* __restrict__ Wk,
    const float* __restrict__ Wv, const float* __restrict__ Wo,
    float* __restrict__ hh, float* __restrict__ M){
  int b = blockIdx.x*256 + threadIdx.x;
  if (b >= BN) return;
  float hr[10];
  #pragma unroll
  for (int l=0;l<10;l++) hr[l] = h[(size_t)b*10+l];
  float z3[10];
  #pragma unroll
  for (int l=0;l<10;l++) z3[l] = bc[l];
  for (int jc=0;jc<4;jc++){
    float acc[64];
    #pragma unroll
    for (int j=0;j<64;j++) acc[j] = bbf[jc*64+j];
    for (int i=0;i<128;i++){
      float h1 = ba[i];
      #pragma unroll
      for (int l=0;l<10;l++) h1 += hr[l]*WaT[i*10+l];
      h1 = fmaxf(h1, 0.f);
      const float* __restrict__ w = &Wbf[i*256 + jc*64];
      #pragma unroll
      for (int j=0;j<64;j++) acc[j] += h1*w[j];
    }
    #pragma unroll
    for (int j=0;j<64;j++){
      float h2 = fmaxf(acc[j], 0.f);
      const float* __restrict__ wc = &Wc[(jc*64+j)*10];
      #pragma unroll
      for (int l=0;l<10;l++) z3[l] += h2*wc[l];
    }
  }
  float cqk=0.f, cvo=0.f;
  #pragma unroll
  for (int d=0;d<16;d++){ cqk += Wq[d]*Wk[d]; cvo += Wv[d]*Wo[d]; }
  cqk *= 0.25f;
  float y[10];
  attn10(z3, cqk, cvo, y);
  #pragma unroll
  for (int q=0;q<10;q++) hh[(size_t)b*10+q] = y[q];
  moments10(y, M, threadIdx.x & 63);
}

__global__ __launch_bounds__(256) void k_out(
    const float* __restrict__ h,
    const float* __restrict__ WaT, const float* __restrict__ ba,
    const float* __restrict__ Wbf, const float* __restrict__ bbf,
    const float* __restrict__ Wc,  const float* __restrict__ bc,
    float* __restrict__ out){
  int b = blockIdx.x*256 + threadIdx.x;
  if (b >= BN) return;
  float hr[10];
  #pragma unroll
  for (int l=0;l<10;l++) hr[l] = h[(size_t)b*10+l];
  float o0 = bc[0], o1 = bc[1];
  for (int jc=0;jc<4;jc++){
    float acc[64];
    #pragma unroll
    for (int j=0;j<64;j++) acc[j] = bbf[jc*64+j];
    for (int i=0;i<128;i++){
      float h4 = ba[i];
      #pragma unroll
      for (int l=0;l<10;l++) h4 += hr[l]*WaT[i*10+l];
      h4 = fmaxf(h4, 0.f);
      const float* __restrict__ w = &Wbf[i*256 + jc*64];
      #pragma unroll
      for (int j=0;j<64;j++) acc[j] += h4*w[j];
    }
    #pragma unroll
    for (int j=0;j<64;j++){
      float h5 = fmaxf(acc[j], 0.f);
      o0 += h5*Wc[(jc*64+j)*2];
      o1 += h5*Wc[(jc*64+j)*2+1];
    }
  }
  out[(size_t)b*2]   = o0;
  out[(size_t)b*2+1] = o1;
}

extern "C" void kernel_launch(void* const* d_in, const int* in_sizes, int n_in,
                              void* d_out, int out_size, void* d_ws, size_t ws_size,
                              hipStream_t stream){
  const float* x   = (const float*)d_in[0];
  const float* Wq1 = (const float*)d_in[1];
  const float* Wk1 = (const float*)d_in[2];
  const float* Wv1 = (const float*)d_in[3];
  const float* Wo1 = (const float*)d_in[4];
  const float* Wq2 = (const float*)d_in[5];
  const float* Wk2 = (const float*)d_in[6];
  const float* Wv2 = (const float*)d_in[7];
  const float* Wo2 = (const float*)d_in[8];
  const float* W1a = (const float*)d_in[9];  const float* b1a = (const float*)d_in[10];
  const float* g1a = (const float*)d_in[11]; const float* be1a= (const float*)d_in[12];
  const float* W1b = (const float*)d_in[13]; const float* b1b = (const float*)d_in[14];
  const float* g1b = (const float*)d_in[15]; const float* be1b= (const float*)d_in[16];
  const float* W1c = (const float*)d_in[17]; const float* b1c = (const float*)d_in[18];
  const float* W2a = (const float*)d_in[19]; const float* b2a = (const float*)d_in[20];
  const float* g2a = (const float*)d_in[21]; const float* be2a= (const float*)d_in[22];
  const float* W2b = (const float*)d_in[23]; const float* b2b = (const float*)d_in[24];
  const float* g2b = (const float*)d_in[25]; const float* be2b= (const float*)d_in[26];
  const float* W2c = (const float*)d_in[27]; const float* b2c = (const float*)d_in[28];

  float* f   = (float*)d_ws;
  float* h   = f + OFF_H;
  float* hh  = f + OFF_HH;
  float* M1  = f + OFF_M1;
  float* S2  = f + OFF_S2;
  float* M3  = f + OFF_M3;
  float* S4  = f + OFF_S4;
  float* WA1 = f + OFF_WA1; float* BA1 = f + OFF_BA1;
  float* WA2 = f + OFF_WA2; float* BA2 = f + OFF_BA2;
  float* SC2 = f + OFF_SC2; float* TC2 = f + OFF_TC2;
  float* SC4 = f + OFF_SC4; float* TC4 = f + OFF_TC4;
  float* WB1 = f + OFF_WB1; float* BB1 = f + OFF_BB1;
  float* WB2 = f + OFF_WB2; float* BB2 = f + OFF_BB2;
  float* P1  = f + OFF_P1;  float* P3  = f + OFF_P3;
  float* S2B = f + OFF_S2B; float* S4B = f + OFF_S4B;
  unsigned short* WT1 = (unsigned short*)(f + OFF_WT1);
  unsigned short* WT2 = (unsigned short*)(f + OFF_WT2);
  unsigned short* Z = (unsigned short*)((char*)d_ws + OFF_Z_BYTES);

  dim3 grid(BN/256), blk(256);

  if (ws_size >= WS_NEED_MFMA){
    hipMemsetAsync(S2B, 0, (size_t)2*NBKT*512*sizeof(float), stream);
    dim3 gbig(BN/64);
    k_prep_wt<<<128,blk,0,stream>>>(W1b, WT1);
    k_prep_wt<<<128,blk,0,stream>>>(W2b, WT2);
    k_attn_in<<<grid,blk,0,stream>>>(x, Wq1,Wk1,Wv1,Wo1, h, P1);
    k_fold10_part<<<1,128,0,stream>>>(P1, W1a,b1a,g1a,be1a, WA1,BA1);
    k_layer_mfma<<<gbig,blk,0,stream>>>(h, WA1,BA1, WT1,b1b, Z, S2B);
    k_fold_affine<<<1,256,0,stream>>>(S2B, g1b, be1b, SC2, TC2);
    k_consume_mid<<<grid,blk,0,stream>>>(Z, SC2,TC2, W1c,b1c, Wq2,Wk2,Wv2,Wo2, hh, P3);
    k_fold10_part<<<1,128,0,stream>>>(P3, W2a,b2a,g2a,be2a, WA2,BA2);
    k_layer_mfma<<<gbig,blk,0,stream>>>(hh, WA2,BA2, WT2,b2b, Z, S4B);
    k_fold_affine<<<1,256,0,stream>>>(S4B, g2b, be2b, SC4, TC4);
    k_consume_out<<<grid,blk,0,stream>>>(Z, SC4,TC4, W2c,b2c, (float*)d_out);
  } else {
    hipMemsetAsync(M1, 0, (65+512+65+512)*sizeof(float), stream);
    k_attn_in<<<grid,blk,0,stream>>>(x, Wq1,Wk1,Wv1,Wo1, h, P1);
    k_fold10_part<<<1,128,0,stream>>>(P1, W1a,b1a,g1a,be1a, WA1,BA1);
    k_mid<<<grid,blk,0,stream>>>(h, WA1,BA1, W1b,b1b, S2);
    k_fold_big<<<1,256,0,stream>>>(S2, W1b,b1b,g1b,be1b, WB1,BB1);
    k_mid2<<<grid,blk,0,stream>>>(h, WA1,BA1, WB1,BB1, W1c,b1c, Wq2,Wk2,Wv2,Wo2, hh, M3);
    k_fold10_atomic<<<1,128,0,stream>>>(M3, W2a,b2a,g2a,be2a, WA2,BA2);
    k_mid<<<grid,blk,0,stream>>>(hh, WA2,BA2, W2b,b2b, S4);
    k_fold_big<<<1,256,0,stream>>>(S4, W2b,b2b,g2b,be2b, WB2,BB2);
    k_out<<<grid,blk,0,stream>>>(hh, WA2,BA2, WB2,BB2, W2c,b2c, (float*)d_out);
  }
}